// Round 2
// baseline (5459.182 us; speedup 1.0000x reference)
//
#include <hip/hip_runtime.h>
#include <hip/hip_fp16.h>
#include <math.h>

static constexpr int Gd = 64;     // images feature dim
static constexpr int Ed = 32;     // xb feature dim
static constexpr int Kd = 8192;   // codebook size
static constexpr int R  = 4;      // rows per block
static constexpr int T  = 512;    // threads per block
static constexpr int NP = 8;      // pair-chunks per thread (Kd / (2T))
static constexpr float PNULLF = 1e-4f;

// ---- DPP wave reductions (VALU pipe, no LDS traffic) ----
template<int CTRL, int RMASK>
__device__ __forceinline__ float dpp_add(float v) {
  int t = __builtin_amdgcn_update_dpp(0, __builtin_bit_cast(int, v), CTRL, RMASK, 0xf, true);
  return v + __builtin_bit_cast(float, t);
}
template<int CTRL, int RMASK>
__device__ __forceinline__ float dpp_fmax(float v) {
  int t = __builtin_amdgcn_update_dpp(__builtin_bit_cast(int, -__builtin_inff()),
                                      __builtin_bit_cast(int, v), CTRL, RMASK, 0xf, false);
  return fmaxf(v, __builtin_bit_cast(float, t));
}
// total of 64 lanes lands in lane 63
__device__ __forceinline__ float wave_sum(float v) {
  v = dpp_add<0x111, 0xf>(v);  // row_shr:1
  v = dpp_add<0x112, 0xf>(v);  // row_shr:2
  v = dpp_add<0x114, 0xf>(v);  // row_shr:4
  v = dpp_add<0x118, 0xf>(v);  // row_shr:8  -> lanes 15/31/47/63 hold row sums
  v = dpp_add<0x142, 0xa>(v);  // row_bcast:15 -> lanes 31,63 hold half sums
  v = dpp_add<0x143, 0xc>(v);  // row_bcast:31 -> lane 63 holds total
  return v;
}
// 32-lane group sums land in lanes 31 and 63
__device__ __forceinline__ float half_sum(float v) {
  v = dpp_add<0x111, 0xf>(v);
  v = dpp_add<0x112, 0xf>(v);
  v = dpp_add<0x114, 0xf>(v);
  v = dpp_add<0x118, 0xf>(v);
  v = dpp_add<0x142, 0xa>(v);
  return v;
}
__device__ __forceinline__ float wave_max(float v) {
  v = dpp_fmax<0x111, 0xf>(v);
  v = dpp_fmax<0x112, 0xf>(v);
  v = dpp_fmax<0x114, 0xf>(v);
  v = dpp_fmax<0x118, 0xf>(v);
  v = dpp_fmax<0x142, 0xa>(v);
  v = dpp_fmax<0x143, 0xc>(v);
  return v;
}

// ---- weight loaders: HW=true reads f16 cache in d_ws, else original f32 ----
template<bool HW>
__device__ __forceinline__ float2 ldw(const void* p, size_t idx) {
  if constexpr (HW) {
    __half2 h = *reinterpret_cast<const __half2*>(reinterpret_cast<const __half*>(p) + idx);
    return __half22float2(h);
  } else {
    return *reinterpret_cast<const float2*>(reinterpret_cast<const float*>(p) + idx);
  }
}
template<bool HW>
__device__ __forceinline__ float4 ld4w(const void* p, size_t idx) {
  if constexpr (HW) {
    const __half2* ph = reinterpret_cast<const __half2*>(reinterpret_cast<const __half*>(p) + idx);
    float2 a = __half22float2(ph[0]);
    float2 b = __half22float2(ph[1]);
    return make_float4(a.x, a.y, b.x, b.y);
  } else {
    return *reinterpret_cast<const float4*>(reinterpret_cast<const float*>(p) + idx);
  }
}

// LDS float offsets
static constexpr int OFF_LP   = 0;                  // [R][Kd]   32768
static constexpr int OFF_IMG  = 32768;              // [Gd][R]   256
static constexpr int OFF_ZT   = 33024;              // [Ed][R]   128
static constexpr int OFF_WRD  = 33152;              // [8][132]  1056
static constexpr int OFF_MLD  = 34208;              // [4]
static constexpr int OFF_SLD  = 34212;              // [4]
static constexpr int OFF_Z2   = 34216;              // [4]
static constexpr int OFF_X2   = 34220;              // [4]
static constexpr int SMEM_FLOATS = 34224;           // 136896 B

template<bool HW>
__global__ __launch_bounds__(T, 2) void glgae_fused(
    const float* __restrict__ images,
    const void*  __restrict__ xaP,    // f16 (HW) or f32
    const void*  __restrict__ xbP,
    const float* __restrict__ c2aP,   // exact col sums of xa^2 (HW only)
    const float* __restrict__ cb2P,   // exact col sums of xb^2 (HW only)
    const int*   __restrict__ nstep_p,
    float* __restrict__ out)
{
  extern __shared__ float sm[];
  float* LP  = sm + OFF_LP;
  float* IMG = sm + OFF_IMG;
  float* ZT  = sm + OFF_ZT;
  float* WRD = sm + OFF_WRD;
  float* MLD = sm + OFF_MLD;
  float* SLD = sm + OFF_SLD;
  float* Z2L = sm + OFF_Z2;
  float* X2L = sm + OFF_X2;

  const int tid  = (int)threadIdx.x;
  const int lane = tid & 63;
  const int wv   = tid >> 6;
  const int rowbase = (int)blockIdx.x * R;
  const int nstep = nstep_p[0];
  const int kb0 = tid * 2;   // pair base inside each 1024-column chunk

  // ---- stage images transposed: IMG[g][r] ----
  if (tid < Gd * R) {
    int g = tid >> 2, r = tid & 3;
    IMG[g * R + r] = images[(size_t)(rowbase + r) * Gd + g];
  }
  __syncthreads();
  if (tid < R) {
    float s = 0.f;
    #pragma unroll
    for (int g = 0; g < Gd; ++g) { float v = IMG[g * R + tid]; s = fmaf(v, v, s); }
    X2L[tid] = s;
  }

  // ================= phase A: lpik = -(x2 - 2 x.xa + c2)/Gd =================
  float xk[R][NP][2];
  float c2l[NP][2];   // only used when !HW
  #pragma unroll
  for (int r = 0; r < R; ++r)
    #pragma unroll
    for (int i = 0; i < NP; ++i) { xk[r][i][0] = 0.f; xk[r][i][1] = 0.f; }
  #pragma unroll
  for (int i = 0; i < NP; ++i) { c2l[i][0] = 0.f; c2l[i][1] = 0.f; }

  #pragma unroll 2
  for (int g = 0; g < Gd; ++g) {
    float4 imv4 = *reinterpret_cast<const float4*>(&IMG[g * R]);
    float im[4] = {imv4.x, imv4.y, imv4.z, imv4.w};
    #pragma unroll
    for (int i = 0; i < NP; ++i) {
      float2 w = ldw<HW>(xaP, (size_t)g * Kd + i * 1024 + kb0);
      if constexpr (!HW) {
        c2l[i][0] = fmaf(w.x, w.x, c2l[i][0]);
        c2l[i][1] = fmaf(w.y, w.y, c2l[i][1]);
      }
      #pragma unroll
      for (int r = 0; r < R; ++r) {
        xk[r][i][0] = fmaf(im[r], w.x, xk[r][i][0]);
        xk[r][i][1] = fmaf(im[r], w.y, xk[r][i][1]);
      }
    }
  }
  __syncthreads();  // X2L ready

  float mx[R] = {-__builtin_inff(), -__builtin_inff(), -__builtin_inff(), -__builtin_inff()};
  {
    float x2r[R];
    #pragma unroll
    for (int r = 0; r < R; ++r) x2r[r] = X2L[r];
    #pragma unroll
    for (int i = 0; i < NP; ++i) {
      float cx, cy;
      if constexpr (HW) {
        float2 c = *reinterpret_cast<const float2*>(&c2aP[i * 1024 + kb0]);
        cx = c.x; cy = c.y;
      } else { cx = c2l[i][0]; cy = c2l[i][1]; }
      #pragma unroll
      for (int r = 0; r < R; ++r) {
        float v0 = (2.f * xk[r][i][0] - x2r[r] - cx) * (1.f / 64.f);
        float v1 = (2.f * xk[r][i][1] - x2r[r] - cy) * (1.f / 64.f);
        mx[r] = fmaxf(mx[r], fmaxf(v0, v1));
        *reinterpret_cast<float2*>(&LP[r * Kd + i * 1024 + kb0]) = make_float2(v0, v1);
      }
    }
  }
  #pragma unroll
  for (int r = 0; r < R; ++r) mx[r] = wave_max(mx[r]);
  if (lane == 63) {
    #pragma unroll
    for (int r = 0; r < R; ++r) WRD[wv * 132 + 128 + r] = mx[r];
  }
  __syncthreads();
  if (tid < R) {
    float m = -__builtin_inff();
    #pragma unroll
    for (int w = 0; w < 8; ++w) m = fmaxf(m, WRD[w * 132 + 128 + tid]);
    MLD[tid] = m;
  }
  __syncthreads();

  float mr[R];
  #pragma unroll
  for (int r = 0; r < R; ++r) mr[r] = MLD[r];

  // c2 of xb columns for this thread's 16 columns
  float c2v[NP][2];
  #pragma unroll
  for (int i = 0; i < NP; ++i) {
    if constexpr (HW) {
      float2 c = *reinterpret_cast<const float2*>(&cb2P[i * 1024 + kb0]);
      c2v[i][0] = c.x; c2v[i][1] = c.y;
    } else { c2v[i][0] = 0.f; c2v[i][1] = 0.f; }
  }

  // ================= encode: z = softmax(lpik) @ xb^T (M-shifted) =================
  {
    float zacc[R][Ed];
    #pragma unroll
    for (int r = 0; r < R; ++r)
      #pragma unroll
      for (int e = 0; e < Ed; ++e) zacc[r][e] = 0.f;
    float s1[R] = {0.f, 0.f, 0.f, 0.f};

    #pragma unroll
    for (int i = 0; i < NP; ++i) {
      float p[R][2];
      #pragma unroll
      for (int r = 0; r < R; ++r) {
        float2 l = *reinterpret_cast<const float2*>(&LP[r * Kd + i * 1024 + kb0]);
        p[r][0] = __expf(l.x - mr[r]);
        p[r][1] = __expf(l.y - mr[r]);
        s1[r] += p[r][0] + p[r][1];
      }
      #pragma unroll
      for (int e = 0; e < Ed; ++e) {
        float2 w = ldw<HW>(xbP, (size_t)e * Kd + i * 1024 + kb0);
        if constexpr (!HW) {
          c2v[i][0] = fmaf(w.x, w.x, c2v[i][0]);
          c2v[i][1] = fmaf(w.y, w.y, c2v[i][1]);
        }
        #pragma unroll
        for (int r = 0; r < R; ++r) {
          zacc[r][e] = fmaf(p[r][0], w.x, zacc[r][e]);
          zacc[r][e] = fmaf(p[r][1], w.y, zacc[r][e]);
        }
      }
    }

    // fold -cb2/32 into LP once: iterate's exp arg becomes LP' + al + u/16
    #pragma unroll
    for (int i = 0; i < NP; ++i) {
      #pragma unroll
      for (int r = 0; r < R; ++r) {
        float2 l = *reinterpret_cast<const float2*>(&LP[r * Kd + i * 1024 + kb0]);
        l.x -= c2v[i][0] * (1.f / 32.f);
        l.y -= c2v[i][1] * (1.f / 32.f);
        *reinterpret_cast<float2*>(&LP[r * Kd + i * 1024 + kb0]) = l;
      }
    }

    // reduce + init z
    #pragma unroll
    for (int r = 0; r < R; ++r) {
      s1[r] = wave_sum(s1[r]);
      #pragma unroll
      for (int e = 0; e < Ed; ++e) zacc[r][e] = wave_sum(zacc[r][e]);
    }
    if (lane == 63) {
      #pragma unroll
      for (int r = 0; r < R; ++r) {
        #pragma unroll
        for (int e = 0; e < Ed; ++e) WRD[wv * 132 + r * 32 + e] = zacc[r][e];
        WRD[wv * 132 + 128 + r] = s1[r];
      }
    }
    __syncthreads();
    if (tid < 128) {
      int r = tid >> 5, e = tid & 31;
      float zs = 0.f, ss = 0.f;
      #pragma unroll
      for (int w = 0; w < 8; ++w) { zs += WRD[w * 132 + r * 32 + e]; ss += WRD[w * 132 + 128 + r]; }
      float zn = zs / ss;
      ZT[e * R + r] = zn;
      float q = half_sum(zn * zn);
      if ((lane & 31) == 31) Z2L[r] = q;
    }
    __syncthreads();
  }

  // ======== iterate: xp = softmax(lpik + lxqik); z = 0.9 z + 0.1 xp@xb^T ========
  // (concat/log_softmax/P_NULL cancels inside softmax; two-pass per step:
  //  pass U hoists ZT reads e-outer, pass PZ re-reads xb for zacc)
  for (int st = 0; st < nstep; ++st) {
    float al[R];
    #pragma unroll
    for (int r = 0; r < R; ++r) al[r] = fmaf(Z2L[r], -(1.f / 32.f), -mr[r]);

    // ---- pass U: u[r][k] = sum_e z[r][e] * xb[e][k] ----
    float u[R][NP][2];
    #pragma unroll
    for (int r = 0; r < R; ++r)
      #pragma unroll
      for (int i = 0; i < NP; ++i) { u[r][i][0] = 0.f; u[r][i][1] = 0.f; }
    #pragma unroll
    for (int e = 0; e < Ed; ++e) {
      float4 zv = *reinterpret_cast<const float4*>(&ZT[e * R]);  // one broadcast per e
      float z4[4] = {zv.x, zv.y, zv.z, zv.w};
      #pragma unroll
      for (int i = 0; i < NP; ++i) {
        float2 w = ldw<HW>(xbP, (size_t)e * Kd + i * 1024 + kb0);
        #pragma unroll
        for (int r = 0; r < R; ++r) {
          u[r][i][0] = fmaf(z4[r], w.x, u[r][i][0]);
          u[r][i][1] = fmaf(z4[r], w.y, u[r][i][1]);
        }
      }
    }

    // ---- pass PZ: p = exp(LP' + al + u/16); zacc += p * xb ----
    float zacc[R][Ed];
    #pragma unroll
    for (int r = 0; r < R; ++r)
      #pragma unroll
      for (int e = 0; e < Ed; ++e) zacc[r][e] = 0.f;
    float s2[R] = {0.f, 0.f, 0.f, 0.f};

    #pragma unroll
    for (int i = 0; i < NP; ++i) {
      float p[R][2];
      #pragma unroll
      for (int r = 0; r < R; ++r) {
        float2 l = *reinterpret_cast<const float2*>(&LP[r * Kd + i * 1024 + kb0]);
        p[r][0] = __expf(l.x + al[r] + u[r][i][0] * (1.f / 16.f));
        p[r][1] = __expf(l.y + al[r] + u[r][i][1] * (1.f / 16.f));
        s2[r] += p[r][0] + p[r][1];
      }
      #pragma unroll
      for (int e = 0; e < Ed; ++e) {
        float2 w = ldw<HW>(xbP, (size_t)e * Kd + i * 1024 + kb0);
        #pragma unroll
        for (int r = 0; r < R; ++r) {
          zacc[r][e] = fmaf(p[r][0], w.x, zacc[r][e]);
          zacc[r][e] = fmaf(p[r][1], w.y, zacc[r][e]);
        }
      }
    }
    // reduce + blend z
    #pragma unroll
    for (int r = 0; r < R; ++r) {
      s2[r] = wave_sum(s2[r]);
      #pragma unroll
      for (int e = 0; e < Ed; ++e) zacc[r][e] = wave_sum(zacc[r][e]);
    }
    if (lane == 63) {
      #pragma unroll
      for (int r = 0; r < R; ++r) {
        #pragma unroll
        for (int e = 0; e < Ed; ++e) WRD[wv * 132 + r * 32 + e] = zacc[r][e];
        WRD[wv * 132 + 128 + r] = s2[r];
      }
    }
    __syncthreads();
    if (tid < 128) {
      int r = tid >> 5, e = tid & 31;
      float zs = 0.f, ss = 0.f;
      #pragma unroll
      for (int w = 0; w < 8; ++w) { zs += WRD[w * 132 + r * 32 + e]; ss += WRD[w * 132 + 128 + r]; }
      float zn = fmaf(0.1f, zs / ss, 0.9f * ZT[e * R + r]);
      ZT[e * R + r] = zn;
      float q = half_sum(zn * zn);
      if ((lane & 31) == 31) Z2L[r] = q;
    }
    __syncthreads();
  }

  // ================= decode pass 1: xq_unnorm = exp(lxqik(z)), S3 ===================
  {
    float u[R][NP][2];
    #pragma unroll
    for (int r = 0; r < R; ++r)
      #pragma unroll
      for (int i = 0; i < NP; ++i) { u[r][i][0] = 0.f; u[r][i][1] = 0.f; }
    #pragma unroll
    for (int e = 0; e < Ed; ++e) {
      float4 zv = *reinterpret_cast<const float4*>(&ZT[e * R]);
      float z4[4] = {zv.x, zv.y, zv.z, zv.w};
      #pragma unroll
      for (int i = 0; i < NP; ++i) {
        float2 w = ldw<HW>(xbP, (size_t)e * Kd + i * 1024 + kb0);
        #pragma unroll
        for (int r = 0; r < R; ++r) {
          u[r][i][0] = fmaf(z4[r], w.x, u[r][i][0]);
          u[r][i][1] = fmaf(z4[r], w.y, u[r][i][1]);
        }
      }
    }

    float s3[R] = {0.f, 0.f, 0.f, 0.f};
    float nz2[R];
    #pragma unroll
    for (int r = 0; r < R; ++r) nz2[r] = Z2L[r] * -(1.f / 32.f);
    #pragma unroll
    for (int i = 0; i < NP; ++i) {
      #pragma unroll
      for (int r = 0; r < R; ++r) {
        float e0 = __expf(nz2[r] + u[r][i][0] * (1.f / 16.f) - c2v[i][0] * (1.f / 32.f));
        float e1 = __expf(nz2[r] + u[r][i][1] * (1.f / 16.f) - c2v[i][1] * (1.f / 32.f));
        *reinterpret_cast<float2*>(&LP[r * Kd + i * 1024 + kb0]) = make_float2(e0, e1);
        s3[r] += e0 + e1;
      }
    }
    #pragma unroll
    for (int r = 0; r < R; ++r) s3[r] = wave_sum(s3[r]);
    if (lane == 63) {
      #pragma unroll
      for (int r = 0; r < R; ++r) WRD[wv * 132 + 128 + r] = s3[r];
    }
    __syncthreads();
    if (tid < R) {
      float s = 0.f;
      #pragma unroll
      for (int w = 0; w < 8; ++w) s += WRD[w * 132 + 128 + tid];
      SLD[tid] = 1.f / (PNULLF + s);
    }
    __syncthreads();
  }

  // ================= decode pass 2: y = (xq/den) @ xa^T  (wave-per-g) ===============
  {
    float inv[R];
    #pragma unroll
    for (int r = 0; r < R; ++r) inv[r] = SLD[r];
    float acc[R][8];
    #pragma unroll
    for (int r = 0; r < R; ++r)
      #pragma unroll
      for (int gi = 0; gi < 8; ++gi) acc[r][gi] = 0.f;

    #pragma unroll 2
    for (int c = 0; c < 32; ++c) {
      float xq[R][4];
      #pragma unroll
      for (int r = 0; r < R; ++r) {
        float4 q = *reinterpret_cast<const float4*>(&LP[r * Kd + c * 256 + lane * 4]);
        xq[r][0] = q.x; xq[r][1] = q.y; xq[r][2] = q.z; xq[r][3] = q.w;
      }
      #pragma unroll
      for (int gi = 0; gi < 8; ++gi) {
        int g = gi * 8 + wv;
        float4 wa = ld4w<HW>(xaP, (size_t)g * Kd + c * 256 + lane * 4);
        #pragma unroll
        for (int r = 0; r < R; ++r) {
          acc[r][gi] = fmaf(xq[r][0], wa.x, acc[r][gi]);
          acc[r][gi] = fmaf(xq[r][1], wa.y, acc[r][gi]);
          acc[r][gi] = fmaf(xq[r][2], wa.z, acc[r][gi]);
          acc[r][gi] = fmaf(xq[r][3], wa.w, acc[r][gi]);
        }
      }
    }
    #pragma unroll
    for (int r = 0; r < R; ++r)
      #pragma unroll
      for (int gi = 0; gi < 8; ++gi) acc[r][gi] = wave_sum(acc[r][gi]);
    if (lane == 63) {
      #pragma unroll
      for (int r = 0; r < R; ++r)
        #pragma unroll
        for (int gi = 0; gi < 8; ++gi)
          out[(size_t)(rowbase + r) * Gd + gi * 8 + wv] = acc[r][gi] * inv[r];
    }
  }
}

// ---- per-call weight conversion: f32 -> f16 + exact column sums of squares ----
__global__ __launch_bounds__(256) void convert_w(
    const float* __restrict__ xa, const float* __restrict__ xb,
    __half* __restrict__ xah, __half* __restrict__ xbh,
    float* __restrict__ c2a, float* __restrict__ cb2)
{
  int k = (int)(blockIdx.x * blockDim.x + threadIdx.x);
  if (k >= Kd) return;
  float s = 0.f;
  #pragma unroll 4
  for (int g = 0; g < Gd; ++g) {
    float v = xa[(size_t)g * Kd + k];
    xah[(size_t)g * Kd + k] = __float2half(v);
    s = fmaf(v, v, s);
  }
  c2a[k] = s;
  s = 0.f;
  #pragma unroll 4
  for (int e = 0; e < Ed; ++e) {
    float v = xb[(size_t)e * Kd + k];
    xbh[(size_t)e * Kd + k] = __float2half(v);
    s = fmaf(v, v, s);
  }
  cb2[k] = s;
}

extern "C" void kernel_launch(void* const* d_in, const int* in_sizes, int n_in,
                              void* d_out, int out_size, void* d_ws, size_t ws_size,
                              hipStream_t stream) {
  const float* images = (const float*)d_in[0];
  const float* xa     = (const float*)d_in[1];
  const float* xb     = (const float*)d_in[2];
  const int*   nstep  = (const int*)d_in[3];
  float* out = (float*)d_out;

  const size_t smem = (size_t)SMEM_FLOATS * sizeof(float);  // 136896 B
  const size_t need = (size_t)(Gd + Ed) * Kd * sizeof(__half) + (size_t)2 * Kd * sizeof(float);

  if (ws_size >= need) {
    __half* xah = (__half*)d_ws;
    __half* xbh = xah + (size_t)Gd * Kd;
    float*  c2a = (float*)(xbh + (size_t)Ed * Kd);
    float*  cb2 = c2a + Kd;
    hipLaunchKernelGGL(convert_w, dim3(Kd / 256), dim3(256), 0, stream,
                       xa, xb, xah, xbh, c2a, cb2);
    (void)hipFuncSetAttribute((const void*)glgae_fused<true>,
                              hipFuncAttributeMaxDynamicSharedMemorySize, (int)smem);
    hipLaunchKernelGGL(glgae_fused<true>, dim3(4096 / R), dim3(T), smem, stream,
                       images, (const void*)xah, (const void*)xbh, c2a, cb2, nstep, out);
  } else {
    (void)hipFuncSetAttribute((const void*)glgae_fused<false>,
                              hipFuncAttributeMaxDynamicSharedMemorySize, (int)smem);
    hipLaunchKernelGGL(glgae_fused<false>, dim3(4096 / R), dim3(T), smem, stream,
                       images, (const void*)xa, (const void*)xb,
                       (const float*)nullptr, (const float*)nullptr, nstep, out);
  }
}

// Round 3
// 5329.235 us; speedup vs baseline: 1.0244x; 1.0244x over previous
//
#include <hip/hip_runtime.h>
#include <hip/hip_fp16.h>
#include <math.h>

static constexpr int Gd = 64;     // images feature dim
static constexpr int Ed = 32;     // xb feature dim
static constexpr int Kd = 8192;   // codebook size
static constexpr int R  = 4;      // rows per block
static constexpr int T  = 512;    // threads per block
static constexpr int NP = 8;      // pair-chunks per thread (Kd / (2T))
static constexpr float PNULLF = 1e-4f;

// ---- DPP wave reductions (VALU pipe, no LDS traffic) ----
template<int CTRL, int RMASK>
__device__ __forceinline__ float dpp_add(float v) {
  int t = __builtin_amdgcn_update_dpp(0, __builtin_bit_cast(int, v), CTRL, RMASK, 0xf, true);
  return v + __builtin_bit_cast(float, t);
}
template<int CTRL, int RMASK>
__device__ __forceinline__ float dpp_fmax(float v) {
  int t = __builtin_amdgcn_update_dpp(__builtin_bit_cast(int, -__builtin_inff()),
                                      __builtin_bit_cast(int, v), CTRL, RMASK, 0xf, false);
  return fmaxf(v, __builtin_bit_cast(float, t));
}
// total of 64 lanes lands in lane 63
__device__ __forceinline__ float wave_sum(float v) {
  v = dpp_add<0x111, 0xf>(v);  // row_shr:1
  v = dpp_add<0x112, 0xf>(v);  // row_shr:2
  v = dpp_add<0x114, 0xf>(v);  // row_shr:4
  v = dpp_add<0x118, 0xf>(v);  // row_shr:8  -> lanes 15/31/47/63 hold row sums
  v = dpp_add<0x142, 0xa>(v);  // row_bcast:15 -> lanes 31,63 hold half sums
  v = dpp_add<0x143, 0xc>(v);  // row_bcast:31 -> lane 63 holds total
  return v;
}
// 32-lane group sums land in lanes 31 and 63
__device__ __forceinline__ float half_sum(float v) {
  v = dpp_add<0x111, 0xf>(v);
  v = dpp_add<0x112, 0xf>(v);
  v = dpp_add<0x114, 0xf>(v);
  v = dpp_add<0x118, 0xf>(v);
  v = dpp_add<0x142, 0xa>(v);
  return v;
}
__device__ __forceinline__ float wave_max(float v) {
  v = dpp_fmax<0x111, 0xf>(v);
  v = dpp_fmax<0x112, 0xf>(v);
  v = dpp_fmax<0x114, 0xf>(v);
  v = dpp_fmax<0x118, 0xf>(v);
  v = dpp_fmax<0x142, 0xa>(v);
  v = dpp_fmax<0x143, 0xc>(v);
  return v;
}

// ---- weight loaders: HW=true reads f16 cache in d_ws, else original f32 ----
template<bool HW>
__device__ __forceinline__ float2 ldw(const void* p, size_t idx) {
  if constexpr (HW) {
    __half2 h = *reinterpret_cast<const __half2*>(reinterpret_cast<const __half*>(p) + idx);
    return __half22float2(h);
  } else {
    return *reinterpret_cast<const float2*>(reinterpret_cast<const float*>(p) + idx);
  }
}
template<bool HW>
__device__ __forceinline__ float4 ld4w(const void* p, size_t idx) {
  if constexpr (HW) {
    const __half2* ph = reinterpret_cast<const __half2*>(reinterpret_cast<const __half*>(p) + idx);
    float2 a = __half22float2(ph[0]);
    float2 b = __half22float2(ph[1]);
    return make_float4(a.x, a.y, b.x, b.y);
  } else {
    return *reinterpret_cast<const float4*>(reinterpret_cast<const float*>(p) + idx);
  }
}

// LDS float offsets
static constexpr int OFF_LP   = 0;                  // [R][Kd]   32768
static constexpr int OFF_IMG  = 32768;              // [Gd][R]   256
static constexpr int OFF_ZT   = 33024;              // [Ed][R]   128
static constexpr int OFF_WRD  = 33152;              // [8][132]  1056
static constexpr int OFF_MLD  = 34208;              // [4]
static constexpr int OFF_SLD  = 34212;              // [4]
static constexpr int OFF_Z2   = 34216;              // [4]
static constexpr int OFF_X2   = 34220;              // [4]
static constexpr int SMEM_FLOATS = 34224;           // 136896 B

// waves_per_eu(2,2): LDS (137KB) already caps us at 1 block/CU = 2 waves/EU.
// Without the pin, the backend targets 4 waves/EU (128 VGPR) and spills ~24KB
// per thread -> 12.4 GB HBM scratch traffic (measured r2). Pin grants 256 VGPRs.
template<bool HW>
__global__ __launch_bounds__(T) __attribute__((amdgpu_waves_per_eu(2, 2)))
void glgae_fused(
    const float* __restrict__ images,
    const void*  __restrict__ xaP,    // f16 (HW) or f32
    const void*  __restrict__ xbP,
    const float* __restrict__ c2aP,   // exact col sums of xa^2 (HW only)
    const float* __restrict__ cb2P,   // exact col sums of xb^2 (HW only)
    const int*   __restrict__ nstep_p,
    float* __restrict__ out)
{
  extern __shared__ float sm[];
  float* LP  = sm + OFF_LP;
  float* IMG = sm + OFF_IMG;
  float* ZT  = sm + OFF_ZT;
  float* WRD = sm + OFF_WRD;
  float* MLD = sm + OFF_MLD;
  float* SLD = sm + OFF_SLD;
  float* Z2L = sm + OFF_Z2;
  float* X2L = sm + OFF_X2;

  const int tid  = (int)threadIdx.x;
  const int lane = tid & 63;
  const int wv   = tid >> 6;
  const int rowbase = (int)blockIdx.x * R;
  const int nstep = nstep_p[0];
  const int kb0 = tid * 2;   // pair base inside each 1024-column chunk

  // ---- stage images transposed: IMG[g][r] ----
  if (tid < Gd * R) {
    int g = tid >> 2, r = tid & 3;
    IMG[g * R + r] = images[(size_t)(rowbase + r) * Gd + g];
  }
  __syncthreads();
  if (tid < R) {
    float s = 0.f;
    #pragma unroll
    for (int g = 0; g < Gd; ++g) { float v = IMG[g * R + tid]; s = fmaf(v, v, s); }
    X2L[tid] = s;
  }

  // ================= phase A: lpik = -(x2 - 2 x.xa + c2)/Gd =================
  float xk[R][NP][2];
  float c2l[NP][2];   // only used when !HW
  #pragma unroll
  for (int r = 0; r < R; ++r)
    #pragma unroll
    for (int i = 0; i < NP; ++i) { xk[r][i][0] = 0.f; xk[r][i][1] = 0.f; }
  #pragma unroll
  for (int i = 0; i < NP; ++i) { c2l[i][0] = 0.f; c2l[i][1] = 0.f; }

  #pragma unroll 2
  for (int g = 0; g < Gd; ++g) {
    float4 imv4 = *reinterpret_cast<const float4*>(&IMG[g * R]);
    float im[4] = {imv4.x, imv4.y, imv4.z, imv4.w};
    #pragma unroll
    for (int i = 0; i < NP; ++i) {
      float2 w = ldw<HW>(xaP, (size_t)g * Kd + i * 1024 + kb0);
      if constexpr (!HW) {
        c2l[i][0] = fmaf(w.x, w.x, c2l[i][0]);
        c2l[i][1] = fmaf(w.y, w.y, c2l[i][1]);
      }
      #pragma unroll
      for (int r = 0; r < R; ++r) {
        xk[r][i][0] = fmaf(im[r], w.x, xk[r][i][0]);
        xk[r][i][1] = fmaf(im[r], w.y, xk[r][i][1]);
      }
    }
  }
  __syncthreads();  // X2L ready

  float mx[R] = {-__builtin_inff(), -__builtin_inff(), -__builtin_inff(), -__builtin_inff()};
  {
    float x2r[R];
    #pragma unroll
    for (int r = 0; r < R; ++r) x2r[r] = X2L[r];
    #pragma unroll
    for (int i = 0; i < NP; ++i) {
      float cx, cy;
      if constexpr (HW) {
        float2 c = *reinterpret_cast<const float2*>(&c2aP[i * 1024 + kb0]);
        cx = c.x; cy = c.y;
      } else { cx = c2l[i][0]; cy = c2l[i][1]; }
      #pragma unroll
      for (int r = 0; r < R; ++r) {
        float v0 = (2.f * xk[r][i][0] - x2r[r] - cx) * (1.f / 64.f);
        float v1 = (2.f * xk[r][i][1] - x2r[r] - cy) * (1.f / 64.f);
        mx[r] = fmaxf(mx[r], fmaxf(v0, v1));
        *reinterpret_cast<float2*>(&LP[r * Kd + i * 1024 + kb0]) = make_float2(v0, v1);
      }
    }
  }
  #pragma unroll
  for (int r = 0; r < R; ++r) mx[r] = wave_max(mx[r]);
  if (lane == 63) {
    #pragma unroll
    for (int r = 0; r < R; ++r) WRD[wv * 132 + 128 + r] = mx[r];
  }
  __syncthreads();
  if (tid < R) {
    float m = -__builtin_inff();
    #pragma unroll
    for (int w = 0; w < 8; ++w) m = fmaxf(m, WRD[w * 132 + 128 + tid]);
    MLD[tid] = m;
  }
  __syncthreads();

  float mr[R];
  #pragma unroll
  for (int r = 0; r < R; ++r) mr[r] = MLD[r];

  // c2 of xb columns for this thread's 16 columns
  float c2v[NP][2];
  #pragma unroll
  for (int i = 0; i < NP; ++i) {
    if constexpr (HW) {
      float2 c = *reinterpret_cast<const float2*>(&cb2P[i * 1024 + kb0]);
      c2v[i][0] = c.x; c2v[i][1] = c.y;
    } else { c2v[i][0] = 0.f; c2v[i][1] = 0.f; }
  }

  // ================= encode: z = softmax(lpik) @ xb^T (M-shifted) =================
  // e-half-split: zacc[4][16] per half (64 regs, disjoint live ranges) to stay
  // under the 256-VGPR budget; p recomputed per half, s1 accumulated in half 0.
  {
    float s1[R] = {0.f, 0.f, 0.f, 0.f};
    #pragma unroll
    for (int eh = 0; eh < 2; ++eh) {
      float zacc[R][16];
      #pragma unroll
      for (int r = 0; r < R; ++r)
        #pragma unroll
        for (int e2 = 0; e2 < 16; ++e2) zacc[r][e2] = 0.f;

      #pragma unroll
      for (int i = 0; i < NP; ++i) {
        float p[R][2];
        #pragma unroll
        for (int r = 0; r < R; ++r) {
          float2 l = *reinterpret_cast<const float2*>(&LP[r * Kd + i * 1024 + kb0]);
          p[r][0] = __expf(l.x - mr[r]);
          p[r][1] = __expf(l.y - mr[r]);
          if (eh == 0) s1[r] += p[r][0] + p[r][1];
        }
        #pragma unroll
        for (int e2 = 0; e2 < 16; ++e2) {
          int e = eh * 16 + e2;
          float2 w = ldw<HW>(xbP, (size_t)e * Kd + i * 1024 + kb0);
          if constexpr (!HW) {   // each e visited once across halves -> exact
            c2v[i][0] = fmaf(w.x, w.x, c2v[i][0]);
            c2v[i][1] = fmaf(w.y, w.y, c2v[i][1]);
          }
          #pragma unroll
          for (int r = 0; r < R; ++r) {
            zacc[r][e2] = fmaf(p[r][0], w.x, zacc[r][e2]);
            zacc[r][e2] = fmaf(p[r][1], w.y, zacc[r][e2]);
          }
        }
      }
      // reduce this e-half
      #pragma unroll
      for (int r = 0; r < R; ++r)
        #pragma unroll
        for (int e2 = 0; e2 < 16; ++e2) zacc[r][e2] = wave_sum(zacc[r][e2]);
      if (lane == 63) {
        #pragma unroll
        for (int r = 0; r < R; ++r)
          #pragma unroll
          for (int e2 = 0; e2 < 16; ++e2)
            WRD[wv * 132 + r * 32 + eh * 16 + e2] = zacc[r][e2];
      }
    }

    #pragma unroll
    for (int r = 0; r < R; ++r) s1[r] = wave_sum(s1[r]);
    if (lane == 63) {
      #pragma unroll
      for (int r = 0; r < R; ++r) WRD[wv * 132 + 128 + r] = s1[r];
    }

    // fold -cb2/32 into LP once: iterate's exp arg becomes LP' + al + u/16
    #pragma unroll
    for (int i = 0; i < NP; ++i) {
      #pragma unroll
      for (int r = 0; r < R; ++r) {
        float2 l = *reinterpret_cast<const float2*>(&LP[r * Kd + i * 1024 + kb0]);
        l.x -= c2v[i][0] * (1.f / 32.f);
        l.y -= c2v[i][1] * (1.f / 32.f);
        *reinterpret_cast<float2*>(&LP[r * Kd + i * 1024 + kb0]) = l;
      }
    }

    __syncthreads();
    if (tid < 128) {
      int r = tid >> 5, e = tid & 31;
      float zs = 0.f, ss = 0.f;
      #pragma unroll
      for (int w = 0; w < 8; ++w) { zs += WRD[w * 132 + r * 32 + e]; ss += WRD[w * 132 + 128 + r]; }
      float zn = zs / ss;
      ZT[e * R + r] = zn;
      float q = half_sum(zn * zn);
      if ((lane & 31) == 31) Z2L[r] = q;
    }
    __syncthreads();
  }

  // ======== iterate: xp = softmax(lpik + lxqik); z = 0.9 z + 0.1 xp@xb^T ========
  // (concat/log_softmax/P_NULL cancels inside softmax; pass U hoists ZT reads
  //  e-outer; pass PZ is e-half-split for register pressure)
  for (int st = 0; st < nstep; ++st) {
    float al[R];
    #pragma unroll
    for (int r = 0; r < R; ++r) al[r] = fmaf(Z2L[r], -(1.f / 32.f), -mr[r]);

    // ---- pass U: u[r][k] = sum_e z[r][e] * xb[e][k] ----
    float u[R][NP][2];
    #pragma unroll
    for (int r = 0; r < R; ++r)
      #pragma unroll
      for (int i = 0; i < NP; ++i) { u[r][i][0] = 0.f; u[r][i][1] = 0.f; }
    #pragma unroll
    for (int e = 0; e < Ed; ++e) {
      float4 zv = *reinterpret_cast<const float4*>(&ZT[e * R]);  // one broadcast per e
      float z4[4] = {zv.x, zv.y, zv.z, zv.w};
      #pragma unroll
      for (int i = 0; i < NP; ++i) {
        float2 w = ldw<HW>(xbP, (size_t)e * Kd + i * 1024 + kb0);
        #pragma unroll
        for (int r = 0; r < R; ++r) {
          u[r][i][0] = fmaf(z4[r], w.x, u[r][i][0]);
          u[r][i][1] = fmaf(z4[r], w.y, u[r][i][1]);
        }
      }
    }

    // ---- pass PZ: p = exp(LP' + al + u/16); zacc += p * xb (e-half-split) ----
    float s2[R] = {0.f, 0.f, 0.f, 0.f};
    #pragma unroll
    for (int eh = 0; eh < 2; ++eh) {
      float zacc[R][16];
      #pragma unroll
      for (int r = 0; r < R; ++r)
        #pragma unroll
        for (int e2 = 0; e2 < 16; ++e2) zacc[r][e2] = 0.f;

      #pragma unroll
      for (int i = 0; i < NP; ++i) {
        float p[R][2];
        #pragma unroll
        for (int r = 0; r < R; ++r) {
          float2 l = *reinterpret_cast<const float2*>(&LP[r * Kd + i * 1024 + kb0]);
          p[r][0] = __expf(l.x + al[r] + u[r][i][0] * (1.f / 16.f));
          p[r][1] = __expf(l.y + al[r] + u[r][i][1] * (1.f / 16.f));
          if (eh == 0) s2[r] += p[r][0] + p[r][1];
        }
        #pragma unroll
        for (int e2 = 0; e2 < 16; ++e2) {
          int e = eh * 16 + e2;
          float2 w = ldw<HW>(xbP, (size_t)e * Kd + i * 1024 + kb0);
          #pragma unroll
          for (int r = 0; r < R; ++r) {
            zacc[r][e2] = fmaf(p[r][0], w.x, zacc[r][e2]);
            zacc[r][e2] = fmaf(p[r][1], w.y, zacc[r][e2]);
          }
        }
      }
      #pragma unroll
      for (int r = 0; r < R; ++r)
        #pragma unroll
        for (int e2 = 0; e2 < 16; ++e2) zacc[r][e2] = wave_sum(zacc[r][e2]);
      if (lane == 63) {
        #pragma unroll
        for (int r = 0; r < R; ++r)
          #pragma unroll
          for (int e2 = 0; e2 < 16; ++e2)
            WRD[wv * 132 + r * 32 + eh * 16 + e2] = zacc[r][e2];
      }
    }

    #pragma unroll
    for (int r = 0; r < R; ++r) s2[r] = wave_sum(s2[r]);
    if (lane == 63) {
      #pragma unroll
      for (int r = 0; r < R; ++r) WRD[wv * 132 + 128 + r] = s2[r];
    }
    __syncthreads();
    if (tid < 128) {
      int r = tid >> 5, e = tid & 31;
      float zs = 0.f, ss = 0.f;
      #pragma unroll
      for (int w = 0; w < 8; ++w) { zs += WRD[w * 132 + r * 32 + e]; ss += WRD[w * 132 + 128 + r]; }
      float zn = fmaf(0.1f, zs / ss, 0.9f * ZT[e * R + r]);
      ZT[e * R + r] = zn;
      float q = half_sum(zn * zn);
      if ((lane & 31) == 31) Z2L[r] = q;
    }
    __syncthreads();
  }

  // ================= decode pass 1: xq_unnorm = exp(lxqik(z)), S3 ===================
  {
    float u[R][NP][2];
    #pragma unroll
    for (int r = 0; r < R; ++r)
      #pragma unroll
      for (int i = 0; i < NP; ++i) { u[r][i][0] = 0.f; u[r][i][1] = 0.f; }
    #pragma unroll
    for (int e = 0; e < Ed; ++e) {
      float4 zv = *reinterpret_cast<const float4*>(&ZT[e * R]);
      float z4[4] = {zv.x, zv.y, zv.z, zv.w};
      #pragma unroll
      for (int i = 0; i < NP; ++i) {
        float2 w = ldw<HW>(xbP, (size_t)e * Kd + i * 1024 + kb0);
        #pragma unroll
        for (int r = 0; r < R; ++r) {
          u[r][i][0] = fmaf(z4[r], w.x, u[r][i][0]);
          u[r][i][1] = fmaf(z4[r], w.y, u[r][i][1]);
        }
      }
    }

    float s3[R] = {0.f, 0.f, 0.f, 0.f};
    float nz2[R];
    #pragma unroll
    for (int r = 0; r < R; ++r) nz2[r] = Z2L[r] * -(1.f / 32.f);
    #pragma unroll
    for (int i = 0; i < NP; ++i) {
      #pragma unroll
      for (int r = 0; r < R; ++r) {
        float e0 = __expf(nz2[r] + u[r][i][0] * (1.f / 16.f) - c2v[i][0] * (1.f / 32.f));
        float e1 = __expf(nz2[r] + u[r][i][1] * (1.f / 16.f) - c2v[i][1] * (1.f / 32.f));
        *reinterpret_cast<float2*>(&LP[r * Kd + i * 1024 + kb0]) = make_float2(e0, e1);
        s3[r] += e0 + e1;
      }
    }
    #pragma unroll
    for (int r = 0; r < R; ++r) s3[r] = wave_sum(s3[r]);
    if (lane == 63) {
      #pragma unroll
      for (int r = 0; r < R; ++r) WRD[wv * 132 + 128 + r] = s3[r];
    }
    __syncthreads();
    if (tid < R) {
      float s = 0.f;
      #pragma unroll
      for (int w = 0; w < 8; ++w) s += WRD[w * 132 + 128 + tid];
      SLD[tid] = 1.f / (PNULLF + s);
    }
    __syncthreads();
  }

  // ================= decode pass 2: y = (xq/den) @ xa^T  (wave-per-g) ===============
  {
    float inv[R];
    #pragma unroll
    for (int r = 0; r < R; ++r) inv[r] = SLD[r];
    float acc[R][8];
    #pragma unroll
    for (int r = 0; r < R; ++r)
      #pragma unroll
      for (int gi = 0; gi < 8; ++gi) acc[r][gi] = 0.f;

    #pragma unroll 2
    for (int c = 0; c < 32; ++c) {
      float xq[R][4];
      #pragma unroll
      for (int r = 0; r < R; ++r) {
        float4 q = *reinterpret_cast<const float4*>(&LP[r * Kd + c * 256 + lane * 4]);
        xq[r][0] = q.x; xq[r][1] = q.y; xq[r][2] = q.z; xq[r][3] = q.w;
      }
      #pragma unroll
      for (int gi = 0; gi < 8; ++gi) {
        int g = gi * 8 + wv;
        float4 wa = ld4w<HW>(xaP, (size_t)g * Kd + c * 256 + lane * 4);
        #pragma unroll
        for (int r = 0; r < R; ++r) {
          acc[r][gi] = fmaf(xq[r][0], wa.x, acc[r][gi]);
          acc[r][gi] = fmaf(xq[r][1], wa.y, acc[r][gi]);
          acc[r][gi] = fmaf(xq[r][2], wa.z, acc[r][gi]);
          acc[r][gi] = fmaf(xq[r][3], wa.w, acc[r][gi]);
        }
      }
    }
    #pragma unroll
    for (int r = 0; r < R; ++r)
      #pragma unroll
      for (int gi = 0; gi < 8; ++gi) acc[r][gi] = wave_sum(acc[r][gi]);
    if (lane == 63) {
      #pragma unroll
      for (int r = 0; r < R; ++r)
        #pragma unroll
        for (int gi = 0; gi < 8; ++gi)
          out[(size_t)(rowbase + r) * Gd + gi * 8 + wv] = acc[r][gi] * inv[r];
    }
  }
}

// ---- per-call weight conversion: f32 -> f16 + exact column sums of squares ----
__global__ __launch_bounds__(256) void convert_w(
    const float* __restrict__ xa, const float* __restrict__ xb,
    __half* __restrict__ xah, __half* __restrict__ xbh,
    float* __restrict__ c2a, float* __restrict__ cb2)
{
  int k = (int)(blockIdx.x * blockDim.x + threadIdx.x);
  if (k >= Kd) return;
  float s = 0.f;
  #pragma unroll 4
  for (int g = 0; g < Gd; ++g) {
    float v = xa[(size_t)g * Kd + k];
    xah[(size_t)g * Kd + k] = __float2half(v);
    s = fmaf(v, v, s);
  }
  c2a[k] = s;
  s = 0.f;
  #pragma unroll 4
  for (int e = 0; e < Ed; ++e) {
    float v = xb[(size_t)e * Kd + k];
    xbh[(size_t)e * Kd + k] = __float2half(v);
    s = fmaf(v, v, s);
  }
  cb2[k] = s;
}

extern "C" void kernel_launch(void* const* d_in, const int* in_sizes, int n_in,
                              void* d_out, int out_size, void* d_ws, size_t ws_size,
                              hipStream_t stream) {
  const float* images = (const float*)d_in[0];
  const float* xa     = (const float*)d_in[1];
  const float* xb     = (const float*)d_in[2];
  const int*   nstep  = (const int*)d_in[3];
  float* out = (float*)d_out;

  const size_t smem = (size_t)SMEM_FLOATS * sizeof(float);  // 136896 B
  const size_t need = (size_t)(Gd + Ed) * Kd * sizeof(__half) + (size_t)2 * Kd * sizeof(float);

  if (ws_size >= need) {
    __half* xah = (__half*)d_ws;
    __half* xbh = xah + (size_t)Gd * Kd;
    float*  c2a = (float*)(xbh + (size_t)Ed * Kd);
    float*  cb2 = c2a + Kd;
    hipLaunchKernelGGL(convert_w, dim3(Kd / 256), dim3(256), 0, stream,
                       xa, xb, xah, xbh, c2a, cb2);
    (void)hipFuncSetAttribute((const void*)glgae_fused<true>,
                              hipFuncAttributeMaxDynamicSharedMemorySize, (int)smem);
    hipLaunchKernelGGL(glgae_fused<true>, dim3(4096 / R), dim3(T), smem, stream,
                       images, (const void*)xah, (const void*)xbh, c2a, cb2, nstep, out);
  } else {
    (void)hipFuncSetAttribute((const void*)glgae_fused<false>,
                              hipFuncAttributeMaxDynamicSharedMemorySize, (int)smem);
    hipLaunchKernelGGL(glgae_fused<false>, dim3(4096 / R), dim3(T), smem, stream,
                       images, (const void*)xa, (const void*)xb,
                       (const float*)nullptr, (const float*)nullptr, nstep, out);
  }
}

// Round 4
// 2813.204 us; speedup vs baseline: 1.9406x; 1.8944x over previous
//
#include <hip/hip_runtime.h>
#include <hip/hip_fp16.h>
#include <math.h>

static constexpr int Gd = 64;     // images feature dim
static constexpr int Ed = 32;     // xb feature dim
static constexpr int Kd = 8192;   // codebook size
static constexpr int R  = 4;      // rows per block
static constexpr int T  = 1024;   // threads per block (16 waves)
static constexpr int NW = 16;     // waves per block
static constexpr int NP = 4;      // float2 pairs per thread (Kd / (2T))
static constexpr int CS = 2 * T;  // k-chunk stride (2048 columns)
static constexpr int EQ = 8;      // e-chunk size for zacc passes (4 chunks)
static constexpr float PNULLF = 1e-4f;

// ---- DPP wave reductions (VALU pipe, no LDS traffic) ----
template<int CTRL, int RMASK>
__device__ __forceinline__ float dpp_add(float v) {
  int t = __builtin_amdgcn_update_dpp(0, __builtin_bit_cast(int, v), CTRL, RMASK, 0xf, true);
  return v + __builtin_bit_cast(float, t);
}
template<int CTRL, int RMASK>
__device__ __forceinline__ float dpp_fmax(float v) {
  int t = __builtin_amdgcn_update_dpp(__builtin_bit_cast(int, -__builtin_inff()),
                                      __builtin_bit_cast(int, v), CTRL, RMASK, 0xf, false);
  return fmaxf(v, __builtin_bit_cast(float, t));
}
// total of 64 lanes lands in lane 63
__device__ __forceinline__ float wave_sum(float v) {
  v = dpp_add<0x111, 0xf>(v);  // row_shr:1
  v = dpp_add<0x112, 0xf>(v);  // row_shr:2
  v = dpp_add<0x114, 0xf>(v);  // row_shr:4
  v = dpp_add<0x118, 0xf>(v);  // row_shr:8  -> lanes 15/31/47/63 hold row sums
  v = dpp_add<0x142, 0xa>(v);  // row_bcast:15 -> lanes 31,63 hold half sums
  v = dpp_add<0x143, 0xc>(v);  // row_bcast:31 -> lane 63 holds total
  return v;
}
// 32-lane group sums land in lanes 31 and 63
__device__ __forceinline__ float half_sum(float v) {
  v = dpp_add<0x111, 0xf>(v);
  v = dpp_add<0x112, 0xf>(v);
  v = dpp_add<0x114, 0xf>(v);
  v = dpp_add<0x118, 0xf>(v);
  v = dpp_add<0x142, 0xa>(v);
  return v;
}
__device__ __forceinline__ float wave_max(float v) {
  v = dpp_fmax<0x111, 0xf>(v);
  v = dpp_fmax<0x112, 0xf>(v);
  v = dpp_fmax<0x114, 0xf>(v);
  v = dpp_fmax<0x118, 0xf>(v);
  v = dpp_fmax<0x142, 0xa>(v);
  v = dpp_fmax<0x143, 0xc>(v);
  return v;
}

// ---- weight loaders: HW=true reads f16 cache in d_ws, else original f32 ----
template<bool HW>
__device__ __forceinline__ float2 ldw(const void* p, size_t idx) {
  if constexpr (HW) {
    __half2 h = *reinterpret_cast<const __half2*>(reinterpret_cast<const __half*>(p) + idx);
    return __half22float2(h);
  } else {
    return *reinterpret_cast<const float2*>(reinterpret_cast<const float*>(p) + idx);
  }
}
template<bool HW>
__device__ __forceinline__ float4 ld4w(const void* p, size_t idx) {
  if constexpr (HW) {
    const __half2* ph = reinterpret_cast<const __half2*>(reinterpret_cast<const __half*>(p) + idx);
    float2 a = __half22float2(ph[0]);
    float2 b = __half22float2(ph[1]);
    return make_float4(a.x, a.y, b.x, b.y);
  } else {
    return *reinterpret_cast<const float4*>(reinterpret_cast<const float*>(p) + idx);
  }
}

// LDS float offsets
static constexpr int OFF_LP   = 0;                  // [R][Kd]    32768
static constexpr int OFF_IMG  = 32768;              // [Gd][R]    256
static constexpr int OFF_ZT   = 33024;              // [Ed][R]    128
static constexpr int OFF_WRD  = 33152;              // [NW][132]  2112
static constexpr int OFF_MLD  = 35264;              // [4]
static constexpr int OFF_SLD  = 35268;              // [4]
static constexpr int OFF_Z2   = 35272;              // [4]
static constexpr int OFF_X2   = 35276;              // [4]
static constexpr int SMEM_FLOATS = 35280;           // 141120 B

// T=1024 -> HW requires all 16 waves resident on one CU (>=4 waves/EU), which
// matches the compiler's 128-VGPR budget. Kernel is DESIGNED to peak ~92 live
// VGPRs (e-quarter zacc split, halved per-thread k-ownership) -> no spill.
template<bool HW>
__global__ __launch_bounds__(T, 4)
void glgae_fused(
    const float* __restrict__ images,
    const void*  __restrict__ xaP,    // f16 (HW) or f32
    const void*  __restrict__ xbP,
    const float* __restrict__ c2aP,   // exact col sums of xa^2 (HW only)
    const float* __restrict__ cb2P,   // exact col sums of xb^2 (HW only)
    const int*   __restrict__ nstep_p,
    float* __restrict__ out)
{
  extern __shared__ float sm[];
  float* LP  = sm + OFF_LP;
  float* IMG = sm + OFF_IMG;
  float* ZT  = sm + OFF_ZT;
  float* WRD = sm + OFF_WRD;
  float* MLD = sm + OFF_MLD;
  float* SLD = sm + OFF_SLD;
  float* Z2L = sm + OFF_Z2;
  float* X2L = sm + OFF_X2;

  const int tid  = (int)threadIdx.x;
  const int lane = tid & 63;
  const int wv   = tid >> 6;
  const int rowbase = (int)blockIdx.x * R;
  const int nstep = nstep_p[0];
  const int kb0 = tid * 2;   // pair base inside each 2048-column chunk

  // ---- stage images transposed: IMG[g][r] ----
  if (tid < Gd * R) {
    int g = tid >> 2, r = tid & 3;
    IMG[g * R + r] = images[(size_t)(rowbase + r) * Gd + g];
  }
  __syncthreads();
  if (tid < R) {
    float s = 0.f;
    #pragma unroll
    for (int g = 0; g < Gd; ++g) { float v = IMG[g * R + tid]; s = fmaf(v, v, s); }
    X2L[tid] = s;
  }

  // ================= phase A: lpik = -(x2 - 2 x.xa + c2)/Gd =================
  {
    float xk[R][NP][2];
    float c2l[NP][2];   // only used when !HW
    #pragma unroll
    for (int r = 0; r < R; ++r)
      #pragma unroll
      for (int i = 0; i < NP; ++i) { xk[r][i][0] = 0.f; xk[r][i][1] = 0.f; }
    #pragma unroll
    for (int i = 0; i < NP; ++i) { c2l[i][0] = 0.f; c2l[i][1] = 0.f; }

    #pragma unroll 4
    for (int g = 0; g < Gd; ++g) {
      float4 imv4 = *reinterpret_cast<const float4*>(&IMG[g * R]);
      float im[4] = {imv4.x, imv4.y, imv4.z, imv4.w};
      #pragma unroll
      for (int i = 0; i < NP; ++i) {
        float2 w = ldw<HW>(xaP, (size_t)g * Kd + i * CS + kb0);
        if constexpr (!HW) {
          c2l[i][0] = fmaf(w.x, w.x, c2l[i][0]);
          c2l[i][1] = fmaf(w.y, w.y, c2l[i][1]);
        }
        #pragma unroll
        for (int r = 0; r < R; ++r) {
          xk[r][i][0] = fmaf(im[r], w.x, xk[r][i][0]);
          xk[r][i][1] = fmaf(im[r], w.y, xk[r][i][1]);
        }
      }
    }
    __syncthreads();  // X2L ready

    float mx[R] = {-__builtin_inff(), -__builtin_inff(), -__builtin_inff(), -__builtin_inff()};
    float x2r[R];
    #pragma unroll
    for (int r = 0; r < R; ++r) x2r[r] = X2L[r];
    #pragma unroll
    for (int i = 0; i < NP; ++i) {
      float cx, cy;
      if constexpr (HW) {
        float2 c = *reinterpret_cast<const float2*>(&c2aP[i * CS + kb0]);
        cx = c.x; cy = c.y;
      } else { cx = c2l[i][0]; cy = c2l[i][1]; }
      #pragma unroll
      for (int r = 0; r < R; ++r) {
        float v0 = (2.f * xk[r][i][0] - x2r[r] - cx) * (1.f / 64.f);
        float v1 = (2.f * xk[r][i][1] - x2r[r] - cy) * (1.f / 64.f);
        mx[r] = fmaxf(mx[r], fmaxf(v0, v1));
        *reinterpret_cast<float2*>(&LP[r * Kd + i * CS + kb0]) = make_float2(v0, v1);
      }
    }
    #pragma unroll
    for (int r = 0; r < R; ++r) mx[r] = wave_max(mx[r]);
    if (lane == 63) {
      #pragma unroll
      for (int r = 0; r < R; ++r) WRD[wv * 132 + 128 + r] = mx[r];
    }
    __syncthreads();
    if (tid < R) {
      float m = -__builtin_inff();
      #pragma unroll
      for (int w = 0; w < NW; ++w) m = fmaxf(m, WRD[w * 132 + 128 + tid]);
      MLD[tid] = m;
    }
    __syncthreads();
  }

  // ================= encode: z = softmax(lpik) @ xb^T (M-shifted) =================
  // e-quarter split: zacc[4][8] (32 regs); p recomputed per quarter; s1 in q0.
  {
    float mr[R];
    #pragma unroll
    for (int r = 0; r < R; ++r) mr[r] = MLD[r];
    float c2v[NP][2];   // !HW: accumulated here (each e visited once); HW: unused
    #pragma unroll
    for (int i = 0; i < NP; ++i) { c2v[i][0] = 0.f; c2v[i][1] = 0.f; }

    float s1[R] = {0.f, 0.f, 0.f, 0.f};
    #pragma unroll
    for (int eq = 0; eq < Ed / EQ; ++eq) {
      float zacc[R][EQ];
      #pragma unroll
      for (int r = 0; r < R; ++r)
        #pragma unroll
        for (int e2 = 0; e2 < EQ; ++e2) zacc[r][e2] = 0.f;

      #pragma unroll
      for (int i = 0; i < NP; ++i) {
        float p[R][2];
        #pragma unroll
        for (int r = 0; r < R; ++r) {
          float2 l = *reinterpret_cast<const float2*>(&LP[r * Kd + i * CS + kb0]);
          p[r][0] = __expf(l.x - mr[r]);
          p[r][1] = __expf(l.y - mr[r]);
          if (eq == 0) s1[r] += p[r][0] + p[r][1];
        }
        #pragma unroll
        for (int e2 = 0; e2 < EQ; ++e2) {
          int e = eq * EQ + e2;
          float2 w = ldw<HW>(xbP, (size_t)e * Kd + i * CS + kb0);
          if constexpr (!HW) {
            c2v[i][0] = fmaf(w.x, w.x, c2v[i][0]);
            c2v[i][1] = fmaf(w.y, w.y, c2v[i][1]);
          }
          #pragma unroll
          for (int r = 0; r < R; ++r) {
            zacc[r][e2] = fmaf(p[r][0], w.x, zacc[r][e2]);
            zacc[r][e2] = fmaf(p[r][1], w.y, zacc[r][e2]);
          }
        }
      }
      #pragma unroll
      for (int r = 0; r < R; ++r)
        #pragma unroll
        for (int e2 = 0; e2 < EQ; ++e2) zacc[r][e2] = wave_sum(zacc[r][e2]);
      if (lane == 63) {
        #pragma unroll
        for (int r = 0; r < R; ++r)
          #pragma unroll
          for (int e2 = 0; e2 < EQ; ++e2)
            WRD[wv * 132 + r * 32 + eq * EQ + e2] = zacc[r][e2];
      }
    }

    #pragma unroll
    for (int r = 0; r < R; ++r) s1[r] = wave_sum(s1[r]);
    if (lane == 63) {
      #pragma unroll
      for (int r = 0; r < R; ++r) WRD[wv * 132 + 128 + r] = s1[r];
    }

    // fold -cb2/32 into LP once: iterate's exp arg becomes LP' + al + u/16
    #pragma unroll
    for (int i = 0; i < NP; ++i) {
      float cx, cy;
      if constexpr (HW) {
        float2 c = *reinterpret_cast<const float2*>(&cb2P[i * CS + kb0]);
        cx = c.x; cy = c.y;
      } else { cx = c2v[i][0]; cy = c2v[i][1]; }
      #pragma unroll
      for (int r = 0; r < R; ++r) {
        float2 l = *reinterpret_cast<const float2*>(&LP[r * Kd + i * CS + kb0]);
        l.x -= cx * (1.f / 32.f);
        l.y -= cy * (1.f / 32.f);
        *reinterpret_cast<float2*>(&LP[r * Kd + i * CS + kb0]) = l;
      }
    }

    __syncthreads();
    if (tid < 128) {
      int r = tid >> 5, e = tid & 31;
      float zs = 0.f, ss = 0.f;
      #pragma unroll
      for (int w = 0; w < NW; ++w) { zs += WRD[w * 132 + r * 32 + e]; ss += WRD[w * 132 + 128 + r]; }
      float zn = zs / ss;
      ZT[e * R + r] = zn;
      float q = half_sum(zn * zn);
      if ((lane & 31) == 31) Z2L[r] = q;
    }
    __syncthreads();
  }

  // ======== iterate: xp = softmax(lpik + lxqik); z = 0.9 z + 0.1 xp@xb^T ========
  // (concat/log_softmax/P_NULL cancels inside softmax; pass U hoists ZT reads
  //  e-outer; pass PZ is e-quarter-split for register pressure)
  for (int st = 0; st < nstep; ++st) {
    float al[R];
    #pragma unroll
    for (int r = 0; r < R; ++r) al[r] = fmaf(Z2L[r], -(1.f / 32.f), -MLD[r]);

    // ---- pass U: u[r][k] = sum_e z[r][e] * xb[e][k] ----
    float u[R][NP][2];
    #pragma unroll
    for (int r = 0; r < R; ++r)
      #pragma unroll
      for (int i = 0; i < NP; ++i) { u[r][i][0] = 0.f; u[r][i][1] = 0.f; }
    #pragma unroll 8
    for (int e = 0; e < Ed; ++e) {
      float4 zv = *reinterpret_cast<const float4*>(&ZT[e * R]);  // one broadcast per e
      float z4[4] = {zv.x, zv.y, zv.z, zv.w};
      #pragma unroll
      for (int i = 0; i < NP; ++i) {
        float2 w = ldw<HW>(xbP, (size_t)e * Kd + i * CS + kb0);
        #pragma unroll
        for (int r = 0; r < R; ++r) {
          u[r][i][0] = fmaf(z4[r], w.x, u[r][i][0]);
          u[r][i][1] = fmaf(z4[r], w.y, u[r][i][1]);
        }
      }
    }

    // ---- pass PZ: p = exp(LP' + al + u/16); zacc += p * xb (e-quarter-split) ----
    float s2[R] = {0.f, 0.f, 0.f, 0.f};
    #pragma unroll
    for (int eq = 0; eq < Ed / EQ; ++eq) {
      float zacc[R][EQ];
      #pragma unroll
      for (int r = 0; r < R; ++r)
        #pragma unroll
        for (int e2 = 0; e2 < EQ; ++e2) zacc[r][e2] = 0.f;

      #pragma unroll
      for (int i = 0; i < NP; ++i) {
        float p[R][2];
        #pragma unroll
        for (int r = 0; r < R; ++r) {
          float2 l = *reinterpret_cast<const float2*>(&LP[r * Kd + i * CS + kb0]);
          p[r][0] = __expf(l.x + al[r] + u[r][i][0] * (1.f / 16.f));
          p[r][1] = __expf(l.y + al[r] + u[r][i][1] * (1.f / 16.f));
          if (eq == 0) s2[r] += p[r][0] + p[r][1];
        }
        #pragma unroll
        for (int e2 = 0; e2 < EQ; ++e2) {
          int e = eq * EQ + e2;
          float2 w = ldw<HW>(xbP, (size_t)e * Kd + i * CS + kb0);
          #pragma unroll
          for (int r = 0; r < R; ++r) {
            zacc[r][e2] = fmaf(p[r][0], w.x, zacc[r][e2]);
            zacc[r][e2] = fmaf(p[r][1], w.y, zacc[r][e2]);
          }
        }
      }
      #pragma unroll
      for (int r = 0; r < R; ++r)
        #pragma unroll
        for (int e2 = 0; e2 < EQ; ++e2) zacc[r][e2] = wave_sum(zacc[r][e2]);
      if (lane == 63) {
        #pragma unroll
        for (int r = 0; r < R; ++r)
          #pragma unroll
          for (int e2 = 0; e2 < EQ; ++e2)
            WRD[wv * 132 + r * 32 + eq * EQ + e2] = zacc[r][e2];
      }
    }

    #pragma unroll
    for (int r = 0; r < R; ++r) s2[r] = wave_sum(s2[r]);
    if (lane == 63) {
      #pragma unroll
      for (int r = 0; r < R; ++r) WRD[wv * 132 + 128 + r] = s2[r];
    }
    __syncthreads();
    if (tid < 128) {
      int r = tid >> 5, e = tid & 31;
      float zs = 0.f, ss = 0.f;
      #pragma unroll
      for (int w = 0; w < NW; ++w) { zs += WRD[w * 132 + r * 32 + e]; ss += WRD[w * 132 + 128 + r]; }
      float zn = fmaf(0.1f, zs / ss, 0.9f * ZT[e * R + r]);
      ZT[e * R + r] = zn;
      float q = half_sum(zn * zn);
      if ((lane & 31) == 31) Z2L[r] = q;
    }
    __syncthreads();
  }

  // ================= decode pass 1: xq_unnorm = exp(lxqik(z)), S3 ===================
  {
    float u[R][NP][2];
    float cw2[NP][2];  // !HW: w^2 accumulated inline
    #pragma unroll
    for (int r = 0; r < R; ++r)
      #pragma unroll
      for (int i = 0; i < NP; ++i) { u[r][i][0] = 0.f; u[r][i][1] = 0.f; }
    #pragma unroll
    for (int i = 0; i < NP; ++i) { cw2[i][0] = 0.f; cw2[i][1] = 0.f; }

    #pragma unroll 8
    for (int e = 0; e < Ed; ++e) {
      float4 zv = *reinterpret_cast<const float4*>(&ZT[e * R]);
      float z4[4] = {zv.x, zv.y, zv.z, zv.w};
      #pragma unroll
      for (int i = 0; i < NP; ++i) {
        float2 w = ldw<HW>(xbP, (size_t)e * Kd + i * CS + kb0);
        if constexpr (!HW) {
          cw2[i][0] = fmaf(w.x, w.x, cw2[i][0]);
          cw2[i][1] = fmaf(w.y, w.y, cw2[i][1]);
        }
        #pragma unroll
        for (int r = 0; r < R; ++r) {
          u[r][i][0] = fmaf(z4[r], w.x, u[r][i][0]);
          u[r][i][1] = fmaf(z4[r], w.y, u[r][i][1]);
        }
      }
    }

    float s3[R] = {0.f, 0.f, 0.f, 0.f};
    float nz2[R];
    #pragma unroll
    for (int r = 0; r < R; ++r) nz2[r] = Z2L[r] * -(1.f / 32.f);
    #pragma unroll
    for (int i = 0; i < NP; ++i) {
      float cx, cy;
      if constexpr (HW) {
        float2 c = *reinterpret_cast<const float2*>(&cb2P[i * CS + kb0]);
        cx = c.x; cy = c.y;
      } else { cx = cw2[i][0]; cy = cw2[i][1]; }
      #pragma unroll
      for (int r = 0; r < R; ++r) {
        float e0 = __expf(nz2[r] + u[r][i][0] * (1.f / 16.f) - cx * (1.f / 32.f));
        float e1 = __expf(nz2[r] + u[r][i][1] * (1.f / 16.f) - cy * (1.f / 32.f));
        *reinterpret_cast<float2*>(&LP[r * Kd + i * CS + kb0]) = make_float2(e0, e1);
        s3[r] += e0 + e1;
      }
    }
    #pragma unroll
    for (int r = 0; r < R; ++r) s3[r] = wave_sum(s3[r]);
    if (lane == 63) {
      #pragma unroll
      for (int r = 0; r < R; ++r) WRD[wv * 132 + 128 + r] = s3[r];
    }
    __syncthreads();
    if (tid < R) {
      float s = 0.f;
      #pragma unroll
      for (int w = 0; w < NW; ++w) s += WRD[w * 132 + 128 + tid];
      SLD[tid] = 1.f / (PNULLF + s);
    }
    __syncthreads();
  }

  // ================= decode pass 2: y = (xq/den) @ xa^T  (wave-per-g) ===============
  {
    float inv[R];
    #pragma unroll
    for (int r = 0; r < R; ++r) inv[r] = SLD[r];
    float acc[R][4];
    #pragma unroll
    for (int r = 0; r < R; ++r)
      #pragma unroll
      for (int gi = 0; gi < 4; ++gi) acc[r][gi] = 0.f;

    #pragma unroll 2
    for (int c = 0; c < 32; ++c) {
      float xq[R][4];
      #pragma unroll
      for (int r = 0; r < R; ++r) {
        float4 q = *reinterpret_cast<const float4*>(&LP[r * Kd + c * 256 + lane * 4]);
        xq[r][0] = q.x; xq[r][1] = q.y; xq[r][2] = q.z; xq[r][3] = q.w;
      }
      #pragma unroll
      for (int gi = 0; gi < 4; ++gi) {
        int g = gi * NW + wv;
        float4 wa = ld4w<HW>(xaP, (size_t)g * Kd + c * 256 + lane * 4);
        #pragma unroll
        for (int r = 0; r < R; ++r) {
          acc[r][gi] = fmaf(xq[r][0], wa.x, acc[r][gi]);
          acc[r][gi] = fmaf(xq[r][1], wa.y, acc[r][gi]);
          acc[r][gi] = fmaf(xq[r][2], wa.z, acc[r][gi]);
          acc[r][gi] = fmaf(xq[r][3], wa.w, acc[r][gi]);
        }
      }
    }
    #pragma unroll
    for (int r = 0; r < R; ++r)
      #pragma unroll
      for (int gi = 0; gi < 4; ++gi) acc[r][gi] = wave_sum(acc[r][gi]);
    if (lane == 63) {
      #pragma unroll
      for (int r = 0; r < R; ++r)
        #pragma unroll
        for (int gi = 0; gi < 4; ++gi)
          out[(size_t)(rowbase + r) * Gd + gi * NW + wv] = acc[r][gi] * inv[r];
    }
  }
}

// ---- per-call weight conversion: f32 -> f16 + exact column sums of squares ----
__global__ __launch_bounds__(256) void convert_w(
    const float* __restrict__ xa, const float* __restrict__ xb,
    __half* __restrict__ xah, __half* __restrict__ xbh,
    float* __restrict__ c2a, float* __restrict__ cb2)
{
  int k = (int)(blockIdx.x * blockDim.x + threadIdx.x);
  if (k >= Kd) return;
  float s = 0.f;
  #pragma unroll 4
  for (int g = 0; g < Gd; ++g) {
    float v = xa[(size_t)g * Kd + k];
    xah[(size_t)g * Kd + k] = __float2half(v);
    s = fmaf(v, v, s);
  }
  c2a[k] = s;
  s = 0.f;
  #pragma unroll 4
  for (int e = 0; e < Ed; ++e) {
    float v = xb[(size_t)e * Kd + k];
    xbh[(size_t)e * Kd + k] = __float2half(v);
    s = fmaf(v, v, s);
  }
  cb2[k] = s;
}

extern "C" void kernel_launch(void* const* d_in, const int* in_sizes, int n_in,
                              void* d_out, int out_size, void* d_ws, size_t ws_size,
                              hipStream_t stream) {
  const float* images = (const float*)d_in[0];
  const float* xa     = (const float*)d_in[1];
  const float* xb     = (const float*)d_in[2];
  const int*   nstep  = (const int*)d_in[3];
  float* out = (float*)d_out;

  const size_t smem = (size_t)SMEM_FLOATS * sizeof(float);  // 141120 B
  const size_t need = (size_t)(Gd + Ed) * Kd * sizeof(__half) + (size_t)2 * Kd * sizeof(float);

  if (ws_size >= need) {
    __half* xah = (__half*)d_ws;
    __half* xbh = xah + (size_t)Gd * Kd;
    float*  c2a = (float*)(xbh + (size_t)Ed * Kd);
    float*  cb2 = c2a + Kd;
    hipLaunchKernelGGL(convert_w, dim3(Kd / 256), dim3(256), 0, stream,
                       xa, xb, xah, xbh, c2a, cb2);
    (void)hipFuncSetAttribute((const void*)glgae_fused<true>,
                              hipFuncAttributeMaxDynamicSharedMemorySize, (int)smem);
    hipLaunchKernelGGL(glgae_fused<true>, dim3(4096 / R), dim3(T), smem, stream,
                       images, (const void*)xah, (const void*)xbh, c2a, cb2, nstep, out);
  } else {
    (void)hipFuncSetAttribute((const void*)glgae_fused<false>,
                              hipFuncAttributeMaxDynamicSharedMemorySize, (int)smem);
    hipLaunchKernelGGL(glgae_fused<false>, dim3(4096 / R), dim3(T), smem, stream,
                       images, (const void*)xa, (const void*)xb,
                       (const float*)nullptr, (const float*)nullptr, nstep, out);
  }
}

// Round 5
// 1890.722 us; speedup vs baseline: 2.8874x; 1.4879x over previous
//
#include <hip/hip_runtime.h>
#include <hip/hip_fp16.h>
#include <math.h>

static constexpr int Gd = 64;     // images feature dim
static constexpr int Ed = 32;     // xb feature dim
static constexpr int Kd = 8192;   // codebook size
static constexpr int R  = 4;      // rows per block
static constexpr int T  = 1024;   // threads per block (16 waves)
static constexpr int NW = 16;     // waves per block
static constexpr int NP = 4;      // float2 pairs per thread (Kd / (2T))
static constexpr int CS = 2 * T;  // k-chunk stride (2048 columns)
static constexpr int EQ = 4;      // e-chunk size for zacc passes (8 chunks)
static constexpr int NEQ = Ed / EQ;
static constexpr float PNULLF = 1e-4f;

// ---- DPP wave reductions (VALU pipe, no LDS traffic) ----
template<int CTRL, int RMASK>
__device__ __forceinline__ float dpp_add(float v) {
  int t = __builtin_amdgcn_update_dpp(0, __builtin_bit_cast(int, v), CTRL, RMASK, 0xf, true);
  return v + __builtin_bit_cast(float, t);
}
template<int CTRL, int RMASK>
__device__ __forceinline__ float dpp_fmax(float v) {
  int t = __builtin_amdgcn_update_dpp(__builtin_bit_cast(int, -__builtin_inff()),
                                      __builtin_bit_cast(int, v), CTRL, RMASK, 0xf, false);
  return fmaxf(v, __builtin_bit_cast(float, t));
}
// total of 64 lanes lands in lane 63
__device__ __forceinline__ float wave_sum(float v) {
  v = dpp_add<0x111, 0xf>(v);  // row_shr:1
  v = dpp_add<0x112, 0xf>(v);  // row_shr:2
  v = dpp_add<0x114, 0xf>(v);  // row_shr:4
  v = dpp_add<0x118, 0xf>(v);  // row_shr:8  -> lanes 15/31/47/63 hold row sums
  v = dpp_add<0x142, 0xa>(v);  // row_bcast:15 -> lanes 31,63 hold half sums
  v = dpp_add<0x143, 0xc>(v);  // row_bcast:31 -> lane 63 holds total
  return v;
}
// 32-lane group sums land in lanes 31 and 63
__device__ __forceinline__ float half_sum(float v) {
  v = dpp_add<0x111, 0xf>(v);
  v = dpp_add<0x112, 0xf>(v);
  v = dpp_add<0x114, 0xf>(v);
  v = dpp_add<0x118, 0xf>(v);
  v = dpp_add<0x142, 0xa>(v);
  return v;
}
__device__ __forceinline__ float wave_max(float v) {
  v = dpp_fmax<0x111, 0xf>(v);
  v = dpp_fmax<0x112, 0xf>(v);
  v = dpp_fmax<0x114, 0xf>(v);
  v = dpp_fmax<0x118, 0xf>(v);
  v = dpp_fmax<0x142, 0xa>(v);
  v = dpp_fmax<0x143, 0xc>(v);
  return v;
}

// ---- weight loaders: HW=true reads f16 cache in d_ws, else original f32 ----
template<bool HW>
__device__ __forceinline__ float2 ldw(const void* p, size_t idx) {
  if constexpr (HW) {
    __half2 h = *reinterpret_cast<const __half2*>(reinterpret_cast<const __half*>(p) + idx);
    return __half22float2(h);
  } else {
    return *reinterpret_cast<const float2*>(reinterpret_cast<const float*>(p) + idx);
  }
}
template<bool HW>
__device__ __forceinline__ float4 ld4w(const void* p, size_t idx) {
  if constexpr (HW) {
    const __half2* ph = reinterpret_cast<const __half2*>(reinterpret_cast<const __half*>(p) + idx);
    float2 a = __half22float2(ph[0]);
    float2 b = __half22float2(ph[1]);
    return make_float4(a.x, a.y, b.x, b.y);
  } else {
    return *reinterpret_cast<const float4*>(reinterpret_cast<const float*>(p) + idx);
  }
}

// LDS float offsets
static constexpr int OFF_LP   = 0;                  // [R][Kd]    32768
static constexpr int OFF_IMG  = 32768;              // [Gd][R]    256
static constexpr int OFF_ZT   = 33024;              // [Ed][R]    128
static constexpr int OFF_WRD  = 33152;              // [NW][132]  2112
static constexpr int OFF_MLD  = 35264;              // [4]
static constexpr int OFF_SLD  = 35268;              // [4]
static constexpr int OFF_Z2   = 35272;              // [4]
static constexpr int OFF_X2   = 35276;              // [4]
static constexpr int SMEM_FLOATS = 35280;           // 141120 B

// Designed for the allocator's 64-VGPR / 8-waves-per-EU target (measured r4):
// u and p are NEVER simultaneously live (u -> p transformed in place), and
// zacc is EQ=4 wide (16 regs). Peak live ~55 VGPRs -> no spill at 64 budget.
template<bool HW>
__global__ __launch_bounds__(T)
void glgae_fused(
    const float* __restrict__ images,
    const void*  __restrict__ xaP,    // f16 (HW) or f32
    const void*  __restrict__ xbP,
    const float* __restrict__ c2aP,   // exact col sums of xa^2 (HW only)
    const float* __restrict__ cb2P,   // exact col sums of xb^2 (HW only)
    const int*   __restrict__ nstep_p,
    float* __restrict__ out)
{
  extern __shared__ float sm[];
  float* LP  = sm + OFF_LP;
  float* IMG = sm + OFF_IMG;
  float* ZT  = sm + OFF_ZT;
  float* WRD = sm + OFF_WRD;
  float* MLD = sm + OFF_MLD;
  float* SLD = sm + OFF_SLD;
  float* Z2L = sm + OFF_Z2;
  float* X2L = sm + OFF_X2;

  const int tid  = (int)threadIdx.x;
  const int lane = tid & 63;
  const int wv   = tid >> 6;
  const int rowbase = (int)blockIdx.x * R;
  const int nstep = nstep_p[0];
  const int kb0 = tid * 2;   // pair base inside each 2048-column chunk

  // ---- stage images transposed: IMG[g][r] ----
  if (tid < Gd * R) {
    int g = tid >> 2, r = tid & 3;
    IMG[g * R + r] = images[(size_t)(rowbase + r) * Gd + g];
  }
  __syncthreads();
  if (tid < R) {
    float s = 0.f;
    #pragma unroll
    for (int g = 0; g < Gd; ++g) { float v = IMG[g * R + tid]; s = fmaf(v, v, s); }
    X2L[tid] = s;
  }

  // ================= phase A: lpik = -(x2 - 2 x.xa + c2)/Gd =================
  {
    float xk[R][NP][2];
    float c2l[NP][2];   // only used when !HW
    #pragma unroll
    for (int r = 0; r < R; ++r)
      #pragma unroll
      for (int i = 0; i < NP; ++i) { xk[r][i][0] = 0.f; xk[r][i][1] = 0.f; }
    #pragma unroll
    for (int i = 0; i < NP; ++i) { c2l[i][0] = 0.f; c2l[i][1] = 0.f; }

    #pragma unroll 2
    for (int g = 0; g < Gd; ++g) {
      float4 imv4 = *reinterpret_cast<const float4*>(&IMG[g * R]);
      float im[4] = {imv4.x, imv4.y, imv4.z, imv4.w};
      #pragma unroll
      for (int i = 0; i < NP; ++i) {
        float2 w = ldw<HW>(xaP, (size_t)g * Kd + i * CS + kb0);
        if constexpr (!HW) {
          c2l[i][0] = fmaf(w.x, w.x, c2l[i][0]);
          c2l[i][1] = fmaf(w.y, w.y, c2l[i][1]);
        }
        #pragma unroll
        for (int r = 0; r < R; ++r) {
          xk[r][i][0] = fmaf(im[r], w.x, xk[r][i][0]);
          xk[r][i][1] = fmaf(im[r], w.y, xk[r][i][1]);
        }
      }
    }
    __syncthreads();  // X2L ready

    float mx[R] = {-__builtin_inff(), -__builtin_inff(), -__builtin_inff(), -__builtin_inff()};
    float x2r[R];
    #pragma unroll
    for (int r = 0; r < R; ++r) x2r[r] = X2L[r];
    #pragma unroll
    for (int i = 0; i < NP; ++i) {
      float cx, cy;
      if constexpr (HW) {
        float2 c = *reinterpret_cast<const float2*>(&c2aP[i * CS + kb0]);
        cx = c.x; cy = c.y;
      } else { cx = c2l[i][0]; cy = c2l[i][1]; }
      #pragma unroll
      for (int r = 0; r < R; ++r) {
        float v0 = (2.f * xk[r][i][0] - x2r[r] - cx) * (1.f / 64.f);
        float v1 = (2.f * xk[r][i][1] - x2r[r] - cy) * (1.f / 64.f);
        mx[r] = fmaxf(mx[r], fmaxf(v0, v1));
        *reinterpret_cast<float2*>(&LP[r * Kd + i * CS + kb0]) = make_float2(v0, v1);
      }
    }
    #pragma unroll
    for (int r = 0; r < R; ++r) mx[r] = wave_max(mx[r]);
    if (lane == 63) {
      #pragma unroll
      for (int r = 0; r < R; ++r) WRD[wv * 132 + 128 + r] = mx[r];
    }
    __syncthreads();
    if (tid < R) {
      float m = -__builtin_inff();
      #pragma unroll
      for (int w = 0; w < NW; ++w) m = fmaxf(m, WRD[w * 132 + 128 + tid]);
      MLD[tid] = m;
    }
    __syncthreads();
  }

  // ================= encode: z = softmax(lpik) @ xb^T (M-shifted) =================
  // p precomputed once (32 regs, one exp/element); zacc is EQ=4 wide (16 regs).
  {
    float p[R][NP][2];
    float s1[R] = {0.f, 0.f, 0.f, 0.f};
    #pragma unroll
    for (int i = 0; i < NP; ++i) {
      #pragma unroll
      for (int r = 0; r < R; ++r) {
        float2 l = *reinterpret_cast<const float2*>(&LP[r * Kd + i * CS + kb0]);
        float m = MLD[r];
        float p0 = __expf(l.x - m);
        float p1 = __expf(l.y - m);
        p[r][i][0] = p0; p[r][i][1] = p1;
        s1[r] += p0 + p1;
      }
    }

    float c2v[NP][2];   // !HW: accumulated below (each e visited once); HW: unused
    #pragma unroll
    for (int i = 0; i < NP; ++i) { c2v[i][0] = 0.f; c2v[i][1] = 0.f; }

    #pragma unroll
    for (int eq = 0; eq < NEQ; ++eq) {
      float zacc[R][EQ];
      #pragma unroll
      for (int r = 0; r < R; ++r)
        #pragma unroll
        for (int e2 = 0; e2 < EQ; ++e2) zacc[r][e2] = 0.f;

      #pragma unroll
      for (int i = 0; i < NP; ++i) {
        #pragma unroll
        for (int e2 = 0; e2 < EQ; ++e2) {
          int e = eq * EQ + e2;
          float2 w = ldw<HW>(xbP, (size_t)e * Kd + i * CS + kb0);
          if constexpr (!HW) {
            c2v[i][0] = fmaf(w.x, w.x, c2v[i][0]);
            c2v[i][1] = fmaf(w.y, w.y, c2v[i][1]);
          }
          #pragma unroll
          for (int r = 0; r < R; ++r) {
            zacc[r][e2] = fmaf(p[r][i][0], w.x, zacc[r][e2]);
            zacc[r][e2] = fmaf(p[r][i][1], w.y, zacc[r][e2]);
          }
        }
      }
      #pragma unroll
      for (int r = 0; r < R; ++r)
        #pragma unroll
        for (int e2 = 0; e2 < EQ; ++e2) zacc[r][e2] = wave_sum(zacc[r][e2]);
      if (lane == 63) {
        #pragma unroll
        for (int r = 0; r < R; ++r)
          #pragma unroll
          for (int e2 = 0; e2 < EQ; ++e2)
            WRD[wv * 132 + r * 32 + eq * EQ + e2] = zacc[r][e2];
      }
    }

    #pragma unroll
    for (int r = 0; r < R; ++r) s1[r] = wave_sum(s1[r]);
    if (lane == 63) {
      #pragma unroll
      for (int r = 0; r < R; ++r) WRD[wv * 132 + 128 + r] = s1[r];
    }

    // fold -cb2/32 into LP once: iterate's exp arg becomes LP' + al + u/16
    #pragma unroll
    for (int i = 0; i < NP; ++i) {
      float cx, cy;
      if constexpr (HW) {
        float2 c = *reinterpret_cast<const float2*>(&cb2P[i * CS + kb0]);
        cx = c.x; cy = c.y;
      } else { cx = c2v[i][0]; cy = c2v[i][1]; }
      #pragma unroll
      for (int r = 0; r < R; ++r) {
        float2 l = *reinterpret_cast<const float2*>(&LP[r * Kd + i * CS + kb0]);
        l.x -= cx * (1.f / 32.f);
        l.y -= cy * (1.f / 32.f);
        *reinterpret_cast<float2*>(&LP[r * Kd + i * CS + kb0]) = l;
      }
    }

    __syncthreads();
    if (tid < 128) {
      int r = tid >> 5, e = tid & 31;
      float zs = 0.f, ss = 0.f;
      #pragma unroll
      for (int w = 0; w < NW; ++w) { zs += WRD[w * 132 + r * 32 + e]; ss += WRD[w * 132 + 128 + r]; }
      float zn = zs / ss;
      ZT[e * R + r] = zn;
      float q = half_sum(zn * zn);
      if ((lane & 31) == 31) Z2L[r] = q;
    }
    __syncthreads();
  }

  // ======== iterate: xp = softmax(lpik + lxqik); z = 0.9 z + 0.1 xp@xb^T ========
  // (concat/log_softmax/P_NULL cancels inside softmax.) Pass U computes u (32
  // regs), then u -> p IN PLACE (u dies, one exp per element), then EQ=4 zacc.
  for (int st = 0; st < nstep; ++st) {
    float al[R];
    #pragma unroll
    for (int r = 0; r < R; ++r) al[r] = fmaf(Z2L[r], -(1.f / 32.f), -MLD[r]);

    // ---- pass U: up[r][k] = sum_e z[r][e] * xb[e][k] ----
    float up[R][NP][2];
    #pragma unroll
    for (int r = 0; r < R; ++r)
      #pragma unroll
      for (int i = 0; i < NP; ++i) { up[r][i][0] = 0.f; up[r][i][1] = 0.f; }
    #pragma unroll 4
    for (int e = 0; e < Ed; ++e) {
      float4 zv = *reinterpret_cast<const float4*>(&ZT[e * R]);  // broadcast
      float z4[4] = {zv.x, zv.y, zv.z, zv.w};
      #pragma unroll
      for (int i = 0; i < NP; ++i) {
        float2 w = ldw<HW>(xbP, (size_t)e * Kd + i * CS + kb0);
        #pragma unroll
        for (int r = 0; r < R; ++r) {
          up[r][i][0] = fmaf(z4[r], w.x, up[r][i][0]);
          up[r][i][1] = fmaf(z4[r], w.y, up[r][i][1]);
        }
      }
    }

    // ---- u -> p in place; s2 ----
    float s2[R] = {0.f, 0.f, 0.f, 0.f};
    #pragma unroll
    for (int i = 0; i < NP; ++i) {
      #pragma unroll
      for (int r = 0; r < R; ++r) {
        float2 l = *reinterpret_cast<const float2*>(&LP[r * Kd + i * CS + kb0]);
        float p0 = __expf(l.x + al[r] + up[r][i][0] * (1.f / 16.f));
        float p1 = __expf(l.y + al[r] + up[r][i][1] * (1.f / 16.f));
        up[r][i][0] = p0; up[r][i][1] = p1;
        s2[r] += p0 + p1;
      }
    }

    // ---- zacc: EQ=4 chunks over e ----
    #pragma unroll
    for (int eq = 0; eq < NEQ; ++eq) {
      float zacc[R][EQ];
      #pragma unroll
      for (int r = 0; r < R; ++r)
        #pragma unroll
        for (int e2 = 0; e2 < EQ; ++e2) zacc[r][e2] = 0.f;

      #pragma unroll
      for (int i = 0; i < NP; ++i) {
        #pragma unroll
        for (int e2 = 0; e2 < EQ; ++e2) {
          int e = eq * EQ + e2;
          float2 w = ldw<HW>(xbP, (size_t)e * Kd + i * CS + kb0);
          #pragma unroll
          for (int r = 0; r < R; ++r) {
            zacc[r][e2] = fmaf(up[r][i][0], w.x, zacc[r][e2]);
            zacc[r][e2] = fmaf(up[r][i][1], w.y, zacc[r][e2]);
          }
        }
      }
      #pragma unroll
      for (int r = 0; r < R; ++r)
        #pragma unroll
        for (int e2 = 0; e2 < EQ; ++e2) zacc[r][e2] = wave_sum(zacc[r][e2]);
      if (lane == 63) {
        #pragma unroll
        for (int r = 0; r < R; ++r)
          #pragma unroll
          for (int e2 = 0; e2 < EQ; ++e2)
            WRD[wv * 132 + r * 32 + eq * EQ + e2] = zacc[r][e2];
      }
    }

    #pragma unroll
    for (int r = 0; r < R; ++r) s2[r] = wave_sum(s2[r]);
    if (lane == 63) {
      #pragma unroll
      for (int r = 0; r < R; ++r) WRD[wv * 132 + 128 + r] = s2[r];
    }
    __syncthreads();
    if (tid < 128) {
      int r = tid >> 5, e = tid & 31;
      float zs = 0.f, ss = 0.f;
      #pragma unroll
      for (int w = 0; w < NW; ++w) { zs += WRD[w * 132 + r * 32 + e]; ss += WRD[w * 132 + 128 + r]; }
      float zn = fmaf(0.1f, zs / ss, 0.9f * ZT[e * R + r]);
      ZT[e * R + r] = zn;
      float q = half_sum(zn * zn);
      if ((lane & 31) == 31) Z2L[r] = q;
    }
    __syncthreads();
  }

  // ================= decode pass 1: xq_unnorm = exp(lxqik(z)), S3 ===================
  {
    float u[R][NP][2];
    float cw2[NP][2];  // !HW: w^2 accumulated inline
    #pragma unroll
    for (int r = 0; r < R; ++r)
      #pragma unroll
      for (int i = 0; i < NP; ++i) { u[r][i][0] = 0.f; u[r][i][1] = 0.f; }
    #pragma unroll
    for (int i = 0; i < NP; ++i) { cw2[i][0] = 0.f; cw2[i][1] = 0.f; }

    #pragma unroll 4
    for (int e = 0; e < Ed; ++e) {
      float4 zv = *reinterpret_cast<const float4*>(&ZT[e * R]);
      float z4[4] = {zv.x, zv.y, zv.z, zv.w};
      #pragma unroll
      for (int i = 0; i < NP; ++i) {
        float2 w = ldw<HW>(xbP, (size_t)e * Kd + i * CS + kb0);
        if constexpr (!HW) {
          cw2[i][0] = fmaf(w.x, w.x, cw2[i][0]);
          cw2[i][1] = fmaf(w.y, w.y, cw2[i][1]);
        }
        #pragma unroll
        for (int r = 0; r < R; ++r) {
          u[r][i][0] = fmaf(z4[r], w.x, u[r][i][0]);
          u[r][i][1] = fmaf(z4[r], w.y, u[r][i][1]);
        }
      }
    }

    float s3[R] = {0.f, 0.f, 0.f, 0.f};
    float nz2[R];
    #pragma unroll
    for (int r = 0; r < R; ++r) nz2[r] = Z2L[r] * -(1.f / 32.f);
    #pragma unroll
    for (int i = 0; i < NP; ++i) {
      float cx, cy;
      if constexpr (HW) {
        float2 c = *reinterpret_cast<const float2*>(&cb2P[i * CS + kb0]);
        cx = c.x; cy = c.y;
      } else { cx = cw2[i][0]; cy = cw2[i][1]; }
      #pragma unroll
      for (int r = 0; r < R; ++r) {
        float e0 = __expf(nz2[r] + u[r][i][0] * (1.f / 16.f) - cx * (1.f / 32.f));
        float e1 = __expf(nz2[r] + u[r][i][1] * (1.f / 16.f) - cy * (1.f / 32.f));
        *reinterpret_cast<float2*>(&LP[r * Kd + i * CS + kb0]) = make_float2(e0, e1);
        s3[r] += e0 + e1;
      }
    }
    #pragma unroll
    for (int r = 0; r < R; ++r) s3[r] = wave_sum(s3[r]);
    if (lane == 63) {
      #pragma unroll
      for (int r = 0; r < R; ++r) WRD[wv * 132 + 128 + r] = s3[r];
    }
    __syncthreads();
    if (tid < R) {
      float s = 0.f;
      #pragma unroll
      for (int w = 0; w < NW; ++w) s += WRD[w * 132 + 128 + tid];
      SLD[tid] = 1.f / (PNULLF + s);
    }
    __syncthreads();
  }

  // ================= decode pass 2: y = (xq/den) @ xa^T  (wave-per-g) ===============
  {
    float inv[R];
    #pragma unroll
    for (int r = 0; r < R; ++r) inv[r] = SLD[r];
    float acc[R][4];
    #pragma unroll
    for (int r = 0; r < R; ++r)
      #pragma unroll
      for (int gi = 0; gi < 4; ++gi) acc[r][gi] = 0.f;

    #pragma unroll 2
    for (int c = 0; c < 32; ++c) {
      float xq[R][4];
      #pragma unroll
      for (int r = 0; r < R; ++r) {
        float4 q = *reinterpret_cast<const float4*>(&LP[r * Kd + c * 256 + lane * 4]);
        xq[r][0] = q.x; xq[r][1] = q.y; xq[r][2] = q.z; xq[r][3] = q.w;
      }
      #pragma unroll
      for (int gi = 0; gi < 4; ++gi) {
        int g = gi * NW + wv;
        float4 wa = ld4w<HW>(xaP, (size_t)g * Kd + c * 256 + lane * 4);
        #pragma unroll
        for (int r = 0; r < R; ++r) {
          acc[r][gi] = fmaf(xq[r][0], wa.x, acc[r][gi]);
          acc[r][gi] = fmaf(xq[r][1], wa.y, acc[r][gi]);
          acc[r][gi] = fmaf(xq[r][2], wa.z, acc[r][gi]);
          acc[r][gi] = fmaf(xq[r][3], wa.w, acc[r][gi]);
        }
      }
    }
    #pragma unroll
    for (int r = 0; r < R; ++r)
      #pragma unroll
      for (int gi = 0; gi < 4; ++gi) acc[r][gi] = wave_sum(acc[r][gi]);
    if (lane == 63) {
      #pragma unroll
      for (int r = 0; r < R; ++r)
        #pragma unroll
        for (int gi = 0; gi < 4; ++gi)
          out[(size_t)(rowbase + r) * Gd + gi * NW + wv] = acc[r][gi] * inv[r];
    }
  }
}

// ---- per-call weight conversion: f32 -> f16 + exact column sums of squares ----
__global__ __launch_bounds__(256) void convert_w(
    const float* __restrict__ xa, const float* __restrict__ xb,
    __half* __restrict__ xah, __half* __restrict__ xbh,
    float* __restrict__ c2a, float* __restrict__ cb2)
{
  int k = (int)(blockIdx.x * blockDim.x + threadIdx.x);
  if (k >= Kd) return;
  float s = 0.f;
  #pragma unroll 4
  for (int g = 0; g < Gd; ++g) {
    float v = xa[(size_t)g * Kd + k];
    xah[(size_t)g * Kd + k] = __float2half(v);
    s = fmaf(v, v, s);
  }
  c2a[k] = s;
  s = 0.f;
  #pragma unroll 4
  for (int e = 0; e < Ed; ++e) {
    float v = xb[(size_t)e * Kd + k];
    xbh[(size_t)e * Kd + k] = __float2half(v);
    s = fmaf(v, v, s);
  }
  cb2[k] = s;
}

extern "C" void kernel_launch(void* const* d_in, const int* in_sizes, int n_in,
                              void* d_out, int out_size, void* d_ws, size_t ws_size,
                              hipStream_t stream) {
  const float* images = (const float*)d_in[0];
  const float* xa     = (const float*)d_in[1];
  const float* xb     = (const float*)d_in[2];
  const int*   nstep  = (const int*)d_in[3];
  float* out = (float*)d_out;

  const size_t smem = (size_t)SMEM_FLOATS * sizeof(float);  // 141120 B
  const size_t need = (size_t)(Gd + Ed) * Kd * sizeof(__half) + (size_t)2 * Kd * sizeof(float);

  if (ws_size >= need) {
    __half* xah = (__half*)d_ws;
    __half* xbh = xah + (size_t)Gd * Kd;
    float*  c2a = (float*)(xbh + (size_t)Ed * Kd);
    float*  cb2 = c2a + Kd;
    hipLaunchKernelGGL(convert_w, dim3(Kd / 256), dim3(256), 0, stream,
                       xa, xb, xah, xbh, c2a, cb2);
    (void)hipFuncSetAttribute((const void*)glgae_fused<true>,
                              hipFuncAttributeMaxDynamicSharedMemorySize, (int)smem);
    hipLaunchKernelGGL(glgae_fused<true>, dim3(4096 / R), dim3(T), smem, stream,
                       images, (const void*)xah, (const void*)xbh, c2a, cb2, nstep, out);
  } else {
    (void)hipFuncSetAttribute((const void*)glgae_fused<false>,
                              hipFuncAttributeMaxDynamicSharedMemorySize, (int)smem);
    hipLaunchKernelGGL(glgae_fused<false>, dim3(4096 / R), dim3(T), smem, stream,
                       images, (const void*)xa, (const void*)xb,
                       (const float*)nullptr, (const float*)nullptr, nstep, out);
  }
}

// Round 6
// 1625.241 us; speedup vs baseline: 3.3590x; 1.1633x over previous
//
#include <hip/hip_runtime.h>
#include <hip/hip_fp16.h>
#include <math.h>

static constexpr int Gd = 64;     // images feature dim
static constexpr int Ed = 32;     // xb feature dim
static constexpr int Kd = 8192;   // codebook size
static constexpr int R  = 4;      // rows per block
static constexpr int T  = 1024;   // threads per block (16 waves)
static constexpr int NW = 16;     // waves per block
static constexpr int NP = 4;      // float2 pairs per thread (Kd / (2T))
static constexpr int CS = 2 * T;  // k-chunk stride (2048 columns)
static constexpr int EQ = 2;      // e-chunk size for zacc passes (16 chunks)
static constexpr int NEQ = Ed / EQ;
static constexpr float PNULLF = 1e-4f;

// ---- DPP wave reductions (VALU pipe, no LDS traffic) ----
template<int CTRL, int RMASK>
__device__ __forceinline__ float dpp_add(float v) {
  int t = __builtin_amdgcn_update_dpp(0, __builtin_bit_cast(int, v), CTRL, RMASK, 0xf, true);
  return v + __builtin_bit_cast(float, t);
}
template<int CTRL, int RMASK>
__device__ __forceinline__ float dpp_fmax(float v) {
  int t = __builtin_amdgcn_update_dpp(__builtin_bit_cast(int, -__builtin_inff()),
                                      __builtin_bit_cast(int, v), CTRL, RMASK, 0xf, false);
  return fmaxf(v, __builtin_bit_cast(float, t));
}
// total of 64 lanes lands in lane 63
__device__ __forceinline__ float wave_sum(float v) {
  v = dpp_add<0x111, 0xf>(v);  // row_shr:1
  v = dpp_add<0x112, 0xf>(v);  // row_shr:2
  v = dpp_add<0x114, 0xf>(v);  // row_shr:4
  v = dpp_add<0x118, 0xf>(v);  // row_shr:8  -> lanes 15/31/47/63 hold row sums
  v = dpp_add<0x142, 0xa>(v);  // row_bcast:15 -> lanes 31,63 hold half sums
  v = dpp_add<0x143, 0xc>(v);  // row_bcast:31 -> lane 63 holds total
  return v;
}
// 32-lane group sums land in lanes 31 and 63
__device__ __forceinline__ float half_sum(float v) {
  v = dpp_add<0x111, 0xf>(v);
  v = dpp_add<0x112, 0xf>(v);
  v = dpp_add<0x114, 0xf>(v);
  v = dpp_add<0x118, 0xf>(v);
  v = dpp_add<0x142, 0xa>(v);
  return v;
}
__device__ __forceinline__ float wave_max(float v) {
  v = dpp_fmax<0x111, 0xf>(v);
  v = dpp_fmax<0x112, 0xf>(v);
  v = dpp_fmax<0x114, 0xf>(v);
  v = dpp_fmax<0x118, 0xf>(v);
  v = dpp_fmax<0x142, 0xa>(v);
  v = dpp_fmax<0x143, 0xc>(v);
  return v;
}

// ---- weight loaders: HW=true reads f16 cache in d_ws, else original f32 ----
template<bool HW>
__device__ __forceinline__ float2 ldw(const void* p, size_t idx) {
  if constexpr (HW) {
    __half2 h = *reinterpret_cast<const __half2*>(reinterpret_cast<const __half*>(p) + idx);
    return __half22float2(h);
  } else {
    return *reinterpret_cast<const float2*>(reinterpret_cast<const float*>(p) + idx);
  }
}
template<bool HW>
__device__ __forceinline__ float4 ld4w(const void* p, size_t idx) {
  if constexpr (HW) {
    const __half2* ph = reinterpret_cast<const __half2*>(reinterpret_cast<const __half*>(p) + idx);
    float2 a = __half22float2(ph[0]);
    float2 b = __half22float2(ph[1]);
    return make_float4(a.x, a.y, b.x, b.y);
  } else {
    return *reinterpret_cast<const float4*>(reinterpret_cast<const float*>(p) + idx);
  }
}

// LDS float offsets
static constexpr int OFF_LP   = 0;                  // [R][Kd]    32768
static constexpr int OFF_IMG  = 32768;              // [Gd][R]    256
static constexpr int OFF_ZT   = 33024;              // [Ed][R]    128
static constexpr int OFF_WRD  = 33152;              // [NW][132]  2112
static constexpr int OFF_MLD  = 35264;              // [4]
static constexpr int OFF_SLD  = 35268;              // [4]
static constexpr int OFF_Z2   = 35272;              // [4]
static constexpr int OFF_X2   = 35276;              // [4]
static constexpr int SMEM_FLOATS = 35280;           // 141120 B

// LDS (141KB) pins 1 block/CU = 16 waves = EXACTLY 4 waves/EU, so a 64-VGPR
// allocation (8 waves/EU target, measured r4/r5) buys zero occupancy and pure
// spill (r5: 1.18GB scratch WRITE). waves_per_eu(4,4) pins the allocator to
// the 128-VGPR budget that matches reality. EQ=2 keeps peak live ~55 as a
// fallback if the attribute is ever ignored (reduction count is EQ-invariant).
template<bool HW>
__global__ __launch_bounds__(T) __attribute__((amdgpu_waves_per_eu(4, 4)))
void glgae_fused(
    const float* __restrict__ images,
    const void*  __restrict__ xaP,    // f16 (HW) or f32
    const void*  __restrict__ xbP,
    const float* __restrict__ c2aP,   // exact col sums of xa^2 (HW only)
    const float* __restrict__ cb2P,   // exact col sums of xb^2 (HW only)
    const int*   __restrict__ nstep_p,
    float* __restrict__ out)
{
  extern __shared__ float sm[];
  float* LP  = sm + OFF_LP;
  float* IMG = sm + OFF_IMG;
  float* ZT  = sm + OFF_ZT;
  float* WRD = sm + OFF_WRD;
  float* MLD = sm + OFF_MLD;
  float* SLD = sm + OFF_SLD;
  float* Z2L = sm + OFF_Z2;
  float* X2L = sm + OFF_X2;

  const int tid  = (int)threadIdx.x;
  const int lane = tid & 63;
  const int wv   = tid >> 6;
  const int rowbase = (int)blockIdx.x * R;
  const int nstep = nstep_p[0];
  const int kb0 = tid * 2;   // pair base inside each 2048-column chunk

  // ---- stage images transposed: IMG[g][r] ----
  if (tid < Gd * R) {
    int g = tid >> 2, r = tid & 3;
    IMG[g * R + r] = images[(size_t)(rowbase + r) * Gd + g];
  }
  __syncthreads();
  if (tid < R) {
    float s = 0.f;
    #pragma unroll
    for (int g = 0; g < Gd; ++g) { float v = IMG[g * R + tid]; s = fmaf(v, v, s); }
    X2L[tid] = s;
  }

  // ================= phase A: lpik = -(x2 - 2 x.xa + c2)/Gd =================
  {
    float xk[R][NP][2];
    float c2l[NP][2];   // only used when !HW
    #pragma unroll
    for (int r = 0; r < R; ++r)
      #pragma unroll
      for (int i = 0; i < NP; ++i) { xk[r][i][0] = 0.f; xk[r][i][1] = 0.f; }
    #pragma unroll
    for (int i = 0; i < NP; ++i) { c2l[i][0] = 0.f; c2l[i][1] = 0.f; }

    #pragma unroll 2
    for (int g = 0; g < Gd; ++g) {
      float4 imv4 = *reinterpret_cast<const float4*>(&IMG[g * R]);
      float im[4] = {imv4.x, imv4.y, imv4.z, imv4.w};
      #pragma unroll
      for (int i = 0; i < NP; ++i) {
        float2 w = ldw<HW>(xaP, (size_t)g * Kd + i * CS + kb0);
        if constexpr (!HW) {
          c2l[i][0] = fmaf(w.x, w.x, c2l[i][0]);
          c2l[i][1] = fmaf(w.y, w.y, c2l[i][1]);
        }
        #pragma unroll
        for (int r = 0; r < R; ++r) {
          xk[r][i][0] = fmaf(im[r], w.x, xk[r][i][0]);
          xk[r][i][1] = fmaf(im[r], w.y, xk[r][i][1]);
        }
      }
    }
    __syncthreads();  // X2L ready

    float mx[R] = {-__builtin_inff(), -__builtin_inff(), -__builtin_inff(), -__builtin_inff()};
    float x2r[R];
    #pragma unroll
    for (int r = 0; r < R; ++r) x2r[r] = X2L[r];
    #pragma unroll
    for (int i = 0; i < NP; ++i) {
      float cx, cy;
      if constexpr (HW) {
        float2 c = *reinterpret_cast<const float2*>(&c2aP[i * CS + kb0]);
        cx = c.x; cy = c.y;
      } else { cx = c2l[i][0]; cy = c2l[i][1]; }
      #pragma unroll
      for (int r = 0; r < R; ++r) {
        float v0 = (2.f * xk[r][i][0] - x2r[r] - cx) * (1.f / 64.f);
        float v1 = (2.f * xk[r][i][1] - x2r[r] - cy) * (1.f / 64.f);
        mx[r] = fmaxf(mx[r], fmaxf(v0, v1));
        *reinterpret_cast<float2*>(&LP[r * Kd + i * CS + kb0]) = make_float2(v0, v1);
      }
    }
    #pragma unroll
    for (int r = 0; r < R; ++r) mx[r] = wave_max(mx[r]);
    if (lane == 63) {
      #pragma unroll
      for (int r = 0; r < R; ++r) WRD[wv * 132 + 128 + r] = mx[r];
    }
    __syncthreads();
    if (tid < R) {
      float m = -__builtin_inff();
      #pragma unroll
      for (int w = 0; w < NW; ++w) m = fmaxf(m, WRD[w * 132 + 128 + tid]);
      MLD[tid] = m;
    }
    __syncthreads();
  }

  // ================= encode: z = softmax(lpik) @ xb^T (M-shifted) =================
  // p precomputed once (32 regs, one exp/element); zacc is EQ=2 wide (8 regs).
  {
    float p[R][NP][2];
    float s1[R] = {0.f, 0.f, 0.f, 0.f};
    #pragma unroll
    for (int i = 0; i < NP; ++i) {
      #pragma unroll
      for (int r = 0; r < R; ++r) {
        float2 l = *reinterpret_cast<const float2*>(&LP[r * Kd + i * CS + kb0]);
        float m = MLD[r];
        float p0 = __expf(l.x - m);
        float p1 = __expf(l.y - m);
        p[r][i][0] = p0; p[r][i][1] = p1;
        s1[r] += p0 + p1;
      }
    }

    float c2v[NP][2];   // !HW: accumulated below (each e visited once); HW: unused
    #pragma unroll
    for (int i = 0; i < NP; ++i) { c2v[i][0] = 0.f; c2v[i][1] = 0.f; }

    #pragma unroll
    for (int eq = 0; eq < NEQ; ++eq) {
      float zacc[R][EQ];
      #pragma unroll
      for (int r = 0; r < R; ++r)
        #pragma unroll
        for (int e2 = 0; e2 < EQ; ++e2) zacc[r][e2] = 0.f;

      #pragma unroll
      for (int i = 0; i < NP; ++i) {
        #pragma unroll
        for (int e2 = 0; e2 < EQ; ++e2) {
          int e = eq * EQ + e2;
          float2 w = ldw<HW>(xbP, (size_t)e * Kd + i * CS + kb0);
          if constexpr (!HW) {
            c2v[i][0] = fmaf(w.x, w.x, c2v[i][0]);
            c2v[i][1] = fmaf(w.y, w.y, c2v[i][1]);
          }
          #pragma unroll
          for (int r = 0; r < R; ++r) {
            zacc[r][e2] = fmaf(p[r][i][0], w.x, zacc[r][e2]);
            zacc[r][e2] = fmaf(p[r][i][1], w.y, zacc[r][e2]);
          }
        }
      }
      #pragma unroll
      for (int r = 0; r < R; ++r)
        #pragma unroll
        for (int e2 = 0; e2 < EQ; ++e2) zacc[r][e2] = wave_sum(zacc[r][e2]);
      if (lane == 63) {
        #pragma unroll
        for (int r = 0; r < R; ++r)
          #pragma unroll
          for (int e2 = 0; e2 < EQ; ++e2)
            WRD[wv * 132 + r * 32 + eq * EQ + e2] = zacc[r][e2];
      }
    }

    #pragma unroll
    for (int r = 0; r < R; ++r) s1[r] = wave_sum(s1[r]);
    if (lane == 63) {
      #pragma unroll
      for (int r = 0; r < R; ++r) WRD[wv * 132 + 128 + r] = s1[r];
    }

    // fold -cb2/32 into LP once: iterate's exp arg becomes LP' + al + u/16
    #pragma unroll
    for (int i = 0; i < NP; ++i) {
      float cx, cy;
      if constexpr (HW) {
        float2 c = *reinterpret_cast<const float2*>(&cb2P[i * CS + kb0]);
        cx = c.x; cy = c.y;
      } else { cx = c2v[i][0]; cy = c2v[i][1]; }
      #pragma unroll
      for (int r = 0; r < R; ++r) {
        float2 l = *reinterpret_cast<const float2*>(&LP[r * Kd + i * CS + kb0]);
        l.x -= cx * (1.f / 32.f);
        l.y -= cy * (1.f / 32.f);
        *reinterpret_cast<float2*>(&LP[r * Kd + i * CS + kb0]) = l;
      }
    }

    __syncthreads();
    if (tid < 128) {
      int r = tid >> 5, e = tid & 31;
      float zs = 0.f, ss = 0.f;
      #pragma unroll
      for (int w = 0; w < NW; ++w) { zs += WRD[w * 132 + r * 32 + e]; ss += WRD[w * 132 + 128 + r]; }
      float zn = zs / ss;
      ZT[e * R + r] = zn;
      float q = half_sum(zn * zn);
      if ((lane & 31) == 31) Z2L[r] = q;
    }
    __syncthreads();
  }

  // ======== iterate: xp = softmax(lpik + lxqik); z = 0.9 z + 0.1 xp@xb^T ========
  // (concat/log_softmax/P_NULL cancels inside softmax.) Pass U computes u (32
  // regs), then u -> p IN PLACE (u dies, one exp per element), then EQ=2 zacc.
  for (int st = 0; st < nstep; ++st) {
    float al[R];
    #pragma unroll
    for (int r = 0; r < R; ++r) al[r] = fmaf(Z2L[r], -(1.f / 32.f), -MLD[r]);

    // ---- pass U: up[r][k] = sum_e z[r][e] * xb[e][k] ----
    float up[R][NP][2];
    #pragma unroll
    for (int r = 0; r < R; ++r)
      #pragma unroll
      for (int i = 0; i < NP; ++i) { up[r][i][0] = 0.f; up[r][i][1] = 0.f; }
    #pragma unroll 4
    for (int e = 0; e < Ed; ++e) {
      float4 zv = *reinterpret_cast<const float4*>(&ZT[e * R]);  // broadcast
      float z4[4] = {zv.x, zv.y, zv.z, zv.w};
      #pragma unroll
      for (int i = 0; i < NP; ++i) {
        float2 w = ldw<HW>(xbP, (size_t)e * Kd + i * CS + kb0);
        #pragma unroll
        for (int r = 0; r < R; ++r) {
          up[r][i][0] = fmaf(z4[r], w.x, up[r][i][0]);
          up[r][i][1] = fmaf(z4[r], w.y, up[r][i][1]);
        }
      }
    }

    // ---- u -> p in place; s2 ----
    float s2[R] = {0.f, 0.f, 0.f, 0.f};
    #pragma unroll
    for (int i = 0; i < NP; ++i) {
      #pragma unroll
      for (int r = 0; r < R; ++r) {
        float2 l = *reinterpret_cast<const float2*>(&LP[r * Kd + i * CS + kb0]);
        float p0 = __expf(l.x + al[r] + up[r][i][0] * (1.f / 16.f));
        float p1 = __expf(l.y + al[r] + up[r][i][1] * (1.f / 16.f));
        up[r][i][0] = p0; up[r][i][1] = p1;
        s2[r] += p0 + p1;
      }
    }

    // ---- zacc: EQ=2 chunks over e ----
    #pragma unroll
    for (int eq = 0; eq < NEQ; ++eq) {
      float zacc[R][EQ];
      #pragma unroll
      for (int r = 0; r < R; ++r)
        #pragma unroll
        for (int e2 = 0; e2 < EQ; ++e2) zacc[r][e2] = 0.f;

      #pragma unroll
      for (int i = 0; i < NP; ++i) {
        #pragma unroll
        for (int e2 = 0; e2 < EQ; ++e2) {
          int e = eq * EQ + e2;
          float2 w = ldw<HW>(xbP, (size_t)e * Kd + i * CS + kb0);
          #pragma unroll
          for (int r = 0; r < R; ++r) {
            zacc[r][e2] = fmaf(up[r][i][0], w.x, zacc[r][e2]);
            zacc[r][e2] = fmaf(up[r][i][1], w.y, zacc[r][e2]);
          }
        }
      }
      #pragma unroll
      for (int r = 0; r < R; ++r)
        #pragma unroll
        for (int e2 = 0; e2 < EQ; ++e2) zacc[r][e2] = wave_sum(zacc[r][e2]);
      if (lane == 63) {
        #pragma unroll
        for (int r = 0; r < R; ++r)
          #pragma unroll
          for (int e2 = 0; e2 < EQ; ++e2)
            WRD[wv * 132 + r * 32 + eq * EQ + e2] = zacc[r][e2];
      }
    }

    #pragma unroll
    for (int r = 0; r < R; ++r) s2[r] = wave_sum(s2[r]);
    if (lane == 63) {
      #pragma unroll
      for (int r = 0; r < R; ++r) WRD[wv * 132 + 128 + r] = s2[r];
    }
    __syncthreads();
    if (tid < 128) {
      int r = tid >> 5, e = tid & 31;
      float zs = 0.f, ss = 0.f;
      #pragma unroll
      for (int w = 0; w < NW; ++w) { zs += WRD[w * 132 + r * 32 + e]; ss += WRD[w * 132 + 128 + r]; }
      float zn = fmaf(0.1f, zs / ss, 0.9f * ZT[e * R + r]);
      ZT[e * R + r] = zn;
      float q = half_sum(zn * zn);
      if ((lane & 31) == 31) Z2L[r] = q;
    }
    __syncthreads();
  }

  // ================= decode pass 1: xq_unnorm = exp(lxqik(z)), S3 ===================
  {
    float u[R][NP][2];
    float cw2[NP][2];  // !HW: w^2 accumulated inline
    #pragma unroll
    for (int r = 0; r < R; ++r)
      #pragma unroll
      for (int i = 0; i < NP; ++i) { u[r][i][0] = 0.f; u[r][i][1] = 0.f; }
    #pragma unroll
    for (int i = 0; i < NP; ++i) { cw2[i][0] = 0.f; cw2[i][1] = 0.f; }

    #pragma unroll 4
    for (int e = 0; e < Ed; ++e) {
      float4 zv = *reinterpret_cast<const float4*>(&ZT[e * R]);
      float z4[4] = {zv.x, zv.y, zv.z, zv.w};
      #pragma unroll
      for (int i = 0; i < NP; ++i) {
        float2 w = ldw<HW>(xbP, (size_t)e * Kd + i * CS + kb0);
        if constexpr (!HW) {
          cw2[i][0] = fmaf(w.x, w.x, cw2[i][0]);
          cw2[i][1] = fmaf(w.y, w.y, cw2[i][1]);
        }
        #pragma unroll
        for (int r = 0; r < R; ++r) {
          u[r][i][0] = fmaf(z4[r], w.x, u[r][i][0]);
          u[r][i][1] = fmaf(z4[r], w.y, u[r][i][1]);
        }
      }
    }

    float s3[R] = {0.f, 0.f, 0.f, 0.f};
    float nz2[R];
    #pragma unroll
    for (int r = 0; r < R; ++r) nz2[r] = Z2L[r] * -(1.f / 32.f);
    #pragma unroll
    for (int i = 0; i < NP; ++i) {
      float cx, cy;
      if constexpr (HW) {
        float2 c = *reinterpret_cast<const float2*>(&cb2P[i * CS + kb0]);
        cx = c.x; cy = c.y;
      } else { cx = cw2[i][0]; cy = cw2[i][1]; }
      #pragma unroll
      for (int r = 0; r < R; ++r) {
        float e0 = __expf(nz2[r] + u[r][i][0] * (1.f / 16.f) - cx * (1.f / 32.f));
        float e1 = __expf(nz2[r] + u[r][i][1] * (1.f / 16.f) - cy * (1.f / 32.f));
        *reinterpret_cast<float2*>(&LP[r * Kd + i * CS + kb0]) = make_float2(e0, e1);
        s3[r] += e0 + e1;
      }
    }
    #pragma unroll
    for (int r = 0; r < R; ++r) s3[r] = wave_sum(s3[r]);
    if (lane == 63) {
      #pragma unroll
      for (int r = 0; r < R; ++r) WRD[wv * 132 + 128 + r] = s3[r];
    }
    __syncthreads();
    if (tid < R) {
      float s = 0.f;
      #pragma unroll
      for (int w = 0; w < NW; ++w) s += WRD[w * 132 + 128 + tid];
      SLD[tid] = 1.f / (PNULLF + s);
    }
    __syncthreads();
  }

  // ================= decode pass 2: y = (xq/den) @ xa^T  (wave-per-g) ===============
  {
    float inv[R];
    #pragma unroll
    for (int r = 0; r < R; ++r) inv[r] = SLD[r];
    float acc[R][4];
    #pragma unroll
    for (int r = 0; r < R; ++r)
      #pragma unroll
      for (int gi = 0; gi < 4; ++gi) acc[r][gi] = 0.f;

    #pragma unroll 2
    for (int c = 0; c < 32; ++c) {
      float xq[R][4];
      #pragma unroll
      for (int r = 0; r < R; ++r) {
        float4 q = *reinterpret_cast<const float4*>(&LP[r * Kd + c * 256 + lane * 4]);
        xq[r][0] = q.x; xq[r][1] = q.y; xq[r][2] = q.z; xq[r][3] = q.w;
      }
      #pragma unroll
      for (int gi = 0; gi < 4; ++gi) {
        int g = gi * NW + wv;
        float4 wa = ld4w<HW>(xaP, (size_t)g * Kd + c * 256 + lane * 4);
        #pragma unroll
        for (int r = 0; r < R; ++r) {
          acc[r][gi] = fmaf(xq[r][0], wa.x, acc[r][gi]);
          acc[r][gi] = fmaf(xq[r][1], wa.y, acc[r][gi]);
          acc[r][gi] = fmaf(xq[r][2], wa.z, acc[r][gi]);
          acc[r][gi] = fmaf(xq[r][3], wa.w, acc[r][gi]);
        }
      }
    }
    #pragma unroll
    for (int r = 0; r < R; ++r)
      #pragma unroll
      for (int gi = 0; gi < 4; ++gi) acc[r][gi] = wave_sum(acc[r][gi]);
    if (lane == 63) {
      #pragma unroll
      for (int r = 0; r < R; ++r)
        #pragma unroll
        for (int gi = 0; gi < 4; ++gi)
          out[(size_t)(rowbase + r) * Gd + gi * NW + wv] = acc[r][gi] * inv[r];
    }
  }
}

// ---- per-call weight conversion: f32 -> f16 + exact column sums of squares ----
__global__ __launch_bounds__(256) void convert_w(
    const float* __restrict__ xa, const float* __restrict__ xb,
    __half* __restrict__ xah, __half* __restrict__ xbh,
    float* __restrict__ c2a, float* __restrict__ cb2)
{
  int k = (int)(blockIdx.x * blockDim.x + threadIdx.x);
  if (k >= Kd) return;
  float s = 0.f;
  #pragma unroll 4
  for (int g = 0; g < Gd; ++g) {
    float v = xa[(size_t)g * Kd + k];
    xah[(size_t)g * Kd + k] = __float2half(v);
    s = fmaf(v, v, s);
  }
  c2a[k] = s;
  s = 0.f;
  #pragma unroll 4
  for (int e = 0; e < Ed; ++e) {
    float v = xb[(size_t)e * Kd + k];
    xbh[(size_t)e * Kd + k] = __float2half(v);
    s = fmaf(v, v, s);
  }
  cb2[k] = s;
}

extern "C" void kernel_launch(void* const* d_in, const int* in_sizes, int n_in,
                              void* d_out, int out_size, void* d_ws, size_t ws_size,
                              hipStream_t stream) {
  const float* images = (const float*)d_in[0];
  const float* xa     = (const float*)d_in[1];
  const float* xb     = (const float*)d_in[2];
  const int*   nstep  = (const int*)d_in[3];
  float* out = (float*)d_out;

  const size_t smem = (size_t)SMEM_FLOATS * sizeof(float);  // 141120 B
  const size_t need = (size_t)(Gd + Ed) * Kd * sizeof(__half) + (size_t)2 * Kd * sizeof(float);

  if (ws_size >= need) {
    __half* xah = (__half*)d_ws;
    __half* xbh = xah + (size_t)Gd * Kd;
    float*  c2a = (float*)(xbh + (size_t)Ed * Kd);
    float*  cb2 = c2a + Kd;
    hipLaunchKernelGGL(convert_w, dim3(Kd / 256), dim3(256), 0, stream,
                       xa, xb, xah, xbh, c2a, cb2);
    (void)hipFuncSetAttribute((const void*)glgae_fused<true>,
                              hipFuncAttributeMaxDynamicSharedMemorySize, (int)smem);
    hipLaunchKernelGGL(glgae_fused<true>, dim3(4096 / R), dim3(T), smem, stream,
                       images, (const void*)xah, (const void*)xbh, c2a, cb2, nstep, out);
  } else {
    (void)hipFuncSetAttribute((const void*)glgae_fused<false>,
                              hipFuncAttributeMaxDynamicSharedMemorySize, (int)smem);
    hipLaunchKernelGGL(glgae_fused<false>, dim3(4096 / R), dim3(T), smem, stream,
                       images, (const void*)xa, (const void*)xb,
                       (const float*)nullptr, (const float*)nullptr, nstep, out);
  }
}

// Round 8
// 838.131 us; speedup vs baseline: 6.5135x; 1.9391x over previous
//
#include <hip/hip_runtime.h>
#include <hip/hip_fp16.h>
#include <math.h>

static constexpr int Gd = 64;     // images feature dim
static constexpr int Ed = 32;     // xb feature dim
static constexpr int Kd = 8192;   // codebook size
static constexpr int R  = 4;      // rows per block
static constexpr int T  = 1024;   // threads per block (16 waves)
static constexpr int NW = 16;     // waves per block
static constexpr int NP = 4;      // float2 pairs per thread (Kd / (2T))
static constexpr int CS = 2 * T;  // k-chunk stride (2048 columns)
static constexpr int EQ = 2;      // e-chunk size for zacc passes (16 chunks)
static constexpr int NEQ = Ed / EQ;
static constexpr float PNULLF = 1e-4f;

// ---- DPP wave reductions (VALU pipe, no LDS traffic) ----
template<int CTRL, int RMASK>
__device__ __forceinline__ float dpp_add(float v) {
  int t = __builtin_amdgcn_update_dpp(0, __builtin_bit_cast(int, v), CTRL, RMASK, 0xf, true);
  return v + __builtin_bit_cast(float, t);
}
template<int CTRL, int RMASK>
__device__ __forceinline__ float dpp_fmax(float v) {
  int t = __builtin_amdgcn_update_dpp(__builtin_bit_cast(int, -__builtin_inff()),
                                      __builtin_bit_cast(int, v), CTRL, RMASK, 0xf, false);
  return fmaxf(v, __builtin_bit_cast(float, t));
}
// total of 64 lanes lands in lane 63
__device__ __forceinline__ float wave_sum(float v) {
  v = dpp_add<0x111, 0xf>(v);  // row_shr:1
  v = dpp_add<0x112, 0xf>(v);  // row_shr:2
  v = dpp_add<0x114, 0xf>(v);  // row_shr:4
  v = dpp_add<0x118, 0xf>(v);  // row_shr:8  -> lanes 15/31/47/63 hold row sums
  v = dpp_add<0x142, 0xa>(v);  // row_bcast:15 -> lanes 31,63 hold half sums
  v = dpp_add<0x143, 0xc>(v);  // row_bcast:31 -> lane 63 holds total
  return v;
}
// 32-lane group sums land in lanes 31 and 63
__device__ __forceinline__ float half_sum(float v) {
  v = dpp_add<0x111, 0xf>(v);
  v = dpp_add<0x112, 0xf>(v);
  v = dpp_add<0x114, 0xf>(v);
  v = dpp_add<0x118, 0xf>(v);
  v = dpp_add<0x142, 0xa>(v);
  return v;
}
__device__ __forceinline__ float wave_max(float v) {
  v = dpp_fmax<0x111, 0xf>(v);
  v = dpp_fmax<0x112, 0xf>(v);
  v = dpp_fmax<0x114, 0xf>(v);
  v = dpp_fmax<0x118, 0xf>(v);
  v = dpp_fmax<0x142, 0xa>(v);
  v = dpp_fmax<0x143, 0xc>(v);
  return v;
}

// ---- weight loaders: HW=true reads f16 cache in d_ws, else original f32 ----
template<bool HW>
__device__ __forceinline__ float2 ldw(const void* p, size_t idx) {
  if constexpr (HW) {
    __half2 h = *reinterpret_cast<const __half2*>(reinterpret_cast<const __half*>(p) + idx);
    return __half22float2(h);
  } else {
    return *reinterpret_cast<const float2*>(reinterpret_cast<const float*>(p) + idx);
  }
}
template<bool HW>
__device__ __forceinline__ float4 ld4w(const void* p, size_t idx) {
  if constexpr (HW) {
    const __half2* ph = reinterpret_cast<const __half2*>(reinterpret_cast<const __half*>(p) + idx);
    float2 a = __half22float2(ph[0]);
    float2 b = __half22float2(ph[1]);
    return make_float4(a.x, a.y, b.x, b.y);
  } else {
    return *reinterpret_cast<const float4*>(reinterpret_cast<const float*>(p) + idx);
  }
}

// LDS float offsets
static constexpr int OFF_LP   = 0;                  // [R][Kd]    32768
static constexpr int OFF_IMG  = 32768;              // [Gd][R]    256
static constexpr int OFF_ZT   = 33024;              // [Ed][R]    128
static constexpr int OFF_WRD  = 33152;              // [NW][132]  2112
static constexpr int OFF_MLD  = 35264;              // [4]
static constexpr int OFF_SLD  = 35268;              // [4]
static constexpr int OFF_Z2   = 35272;              // [4]
static constexpr int OFF_X2   = 35276;              // [4]
static constexpr int SMEM_FLOATS = 35280;           // 141120 B

// LDS (141KB) pins 1 block/CU = 16 waves = EXACTLY 4 waves/EU. r4/r6 showed
// __launch_bounds__ + amdgpu_waves_per_eu conflict -> allocator stuck at 64
// VGPR (8 waves/EU target) and spilled ~1GB. Here: NO __launch_bounds__;
// amdgpu_flat_work_group_size + amdgpu_waves_per_eu(4,4) pin the 128 budget.
// Additionally eq-loops are NOT unrolled (bounded load-hoisting pressure) so
// peak live ~60 fits even a 64-VGPR budget if the attribute is ignored again.
template<bool HW>
__global__ __attribute__((amdgpu_flat_work_group_size(T, T), amdgpu_waves_per_eu(4, 4)))
void glgae_fused(
    const float* __restrict__ images,
    const void*  __restrict__ xaP,    // f16 (HW) or f32
    const void*  __restrict__ xbP,
    const float* __restrict__ c2aP,   // exact col sums of xa^2 (HW only)
    const float* __restrict__ cb2P,   // exact col sums of xb^2 (HW only)
    const int*   __restrict__ nstep_p,
    float* __restrict__ out)
{
  extern __shared__ float sm[];
  float* LP  = sm + OFF_LP;
  float* IMG = sm + OFF_IMG;
  float* ZT  = sm + OFF_ZT;
  float* WRD = sm + OFF_WRD;
  float* MLD = sm + OFF_MLD;
  float* SLD = sm + OFF_SLD;
  float* Z2L = sm + OFF_Z2;
  float* X2L = sm + OFF_X2;

  const int tid  = (int)threadIdx.x;
  const int lane = tid & 63;
  const int wv   = tid >> 6;
  const int rowbase = (int)blockIdx.x * R;
  const int nstep = nstep_p[0];
  const int kb0 = tid * 2;   // pair base inside each 2048-column chunk

  // ---- stage images transposed: IMG[g][r] ----
  if (tid < Gd * R) {
    int g = tid >> 2, r = tid & 3;
    IMG[g * R + r] = images[(size_t)(rowbase + r) * Gd + g];
  }
  __syncthreads();
  if (tid < R) {
    float s = 0.f;
    #pragma unroll
    for (int g = 0; g < Gd; ++g) { float v = IMG[g * R + tid]; s = fmaf(v, v, s); }
    X2L[tid] = s;
  }

  // ================= phase A: lpik = -(x2 - 2 x.xa + c2)/Gd =================
  {
    float xk[R][NP][2];
    float c2l[NP][2];   // only used when !HW
    #pragma unroll
    for (int r = 0; r < R; ++r)
      #pragma unroll
      for (int i = 0; i < NP; ++i) { xk[r][i][0] = 0.f; xk[r][i][1] = 0.f; }
    #pragma unroll
    for (int i = 0; i < NP; ++i) { c2l[i][0] = 0.f; c2l[i][1] = 0.f; }

    #pragma unroll 2
    for (int g = 0; g < Gd; ++g) {
      float4 imv4 = *reinterpret_cast<const float4*>(&IMG[g * R]);
      float im[4] = {imv4.x, imv4.y, imv4.z, imv4.w};
      #pragma unroll
      for (int i = 0; i < NP; ++i) {
        float2 w = ldw<HW>(xaP, (size_t)g * Kd + i * CS + kb0);
        if constexpr (!HW) {
          c2l[i][0] = fmaf(w.x, w.x, c2l[i][0]);
          c2l[i][1] = fmaf(w.y, w.y, c2l[i][1]);
        }
        #pragma unroll
        for (int r = 0; r < R; ++r) {
          xk[r][i][0] = fmaf(im[r], w.x, xk[r][i][0]);
          xk[r][i][1] = fmaf(im[r], w.y, xk[r][i][1]);
        }
      }
    }
    __syncthreads();  // X2L ready

    float mx[R] = {-__builtin_inff(), -__builtin_inff(), -__builtin_inff(), -__builtin_inff()};
    float x2r[R];
    #pragma unroll
    for (int r = 0; r < R; ++r) x2r[r] = X2L[r];
    #pragma unroll
    for (int i = 0; i < NP; ++i) {
      float cx, cy;
      if constexpr (HW) {
        float2 c = *reinterpret_cast<const float2*>(&c2aP[i * CS + kb0]);
        cx = c.x; cy = c.y;
      } else { cx = c2l[i][0]; cy = c2l[i][1]; }
      #pragma unroll
      for (int r = 0; r < R; ++r) {
        float v0 = (2.f * xk[r][i][0] - x2r[r] - cx) * (1.f / 64.f);
        float v1 = (2.f * xk[r][i][1] - x2r[r] - cy) * (1.f / 64.f);
        mx[r] = fmaxf(mx[r], fmaxf(v0, v1));
        *reinterpret_cast<float2*>(&LP[r * Kd + i * CS + kb0]) = make_float2(v0, v1);
      }
    }
    #pragma unroll
    for (int r = 0; r < R; ++r) mx[r] = wave_max(mx[r]);
    if (lane == 63) {
      #pragma unroll
      for (int r = 0; r < R; ++r) WRD[wv * 132 + 128 + r] = mx[r];
    }
    __syncthreads();
    if (tid < R) {
      float m = -__builtin_inff();
      #pragma unroll
      for (int w = 0; w < NW; ++w) m = fmaxf(m, WRD[w * 132 + 128 + tid]);
      MLD[tid] = m;
    }
    __syncthreads();
  }

  // ================= encode: z = softmax(lpik) @ xb^T (M-shifted) =================
  // p precomputed once (32 regs, one exp/element); zacc is EQ=2 wide; eq-loop
  // NOT unrolled -> bounded load-hoisting pressure.
  {
    float p[R][NP][2];
    float s1[R] = {0.f, 0.f, 0.f, 0.f};
    #pragma unroll
    for (int i = 0; i < NP; ++i) {
      #pragma unroll
      for (int r = 0; r < R; ++r) {
        float2 l = *reinterpret_cast<const float2*>(&LP[r * Kd + i * CS + kb0]);
        float m = MLD[r];
        float p0 = __expf(l.x - m);
        float p1 = __expf(l.y - m);
        p[r][i][0] = p0; p[r][i][1] = p1;
        s1[r] += p0 + p1;
      }
    }

    float c2v[NP][2];   // !HW: accumulated below (each e visited once); HW: unused
    #pragma unroll
    for (int i = 0; i < NP; ++i) { c2v[i][0] = 0.f; c2v[i][1] = 0.f; }

    #pragma unroll 1
    for (int eq = 0; eq < NEQ; ++eq) {
      float zacc[R][EQ];
      #pragma unroll
      for (int r = 0; r < R; ++r)
        #pragma unroll
        for (int e2 = 0; e2 < EQ; ++e2) zacc[r][e2] = 0.f;

      #pragma unroll
      for (int i = 0; i < NP; ++i) {
        #pragma unroll
        for (int e2 = 0; e2 < EQ; ++e2) {
          int e = eq * EQ + e2;
          float2 w = ldw<HW>(xbP, (size_t)e * Kd + i * CS + kb0);
          if constexpr (!HW) {
            c2v[i][0] = fmaf(w.x, w.x, c2v[i][0]);
            c2v[i][1] = fmaf(w.y, w.y, c2v[i][1]);
          }
          #pragma unroll
          for (int r = 0; r < R; ++r) {
            zacc[r][e2] = fmaf(p[r][i][0], w.x, zacc[r][e2]);
            zacc[r][e2] = fmaf(p[r][i][1], w.y, zacc[r][e2]);
          }
        }
      }
      #pragma unroll
      for (int r = 0; r < R; ++r)
        #pragma unroll
        for (int e2 = 0; e2 < EQ; ++e2) zacc[r][e2] = wave_sum(zacc[r][e2]);
      if (lane == 63) {
        #pragma unroll
        for (int r = 0; r < R; ++r)
          #pragma unroll
          for (int e2 = 0; e2 < EQ; ++e2)
            WRD[wv * 132 + r * 32 + eq * EQ + e2] = zacc[r][e2];
      }
    }

    #pragma unroll
    for (int r = 0; r < R; ++r) s1[r] = wave_sum(s1[r]);
    if (lane == 63) {
      #pragma unroll
      for (int r = 0; r < R; ++r) WRD[wv * 132 + 128 + r] = s1[r];
    }

    // fold -cb2/32 into LP once: iterate's exp arg becomes LP' + al + u/16
    #pragma unroll
    for (int i = 0; i < NP; ++i) {
      float cx, cy;
      if constexpr (HW) {
        float2 c = *reinterpret_cast<const float2*>(&cb2P[i * CS + kb0]);
        cx = c.x; cy = c.y;
      } else { cx = c2v[i][0]; cy = c2v[i][1]; }
      #pragma unroll
      for (int r = 0; r < R; ++r) {
        float2 l = *reinterpret_cast<const float2*>(&LP[r * Kd + i * CS + kb0]);
        l.x -= cx * (1.f / 32.f);
        l.y -= cy * (1.f / 32.f);
        *reinterpret_cast<float2*>(&LP[r * Kd + i * CS + kb0]) = l;
      }
    }

    __syncthreads();
    if (tid < 128) {
      int r = tid >> 5, e = tid & 31;
      float zs = 0.f, ss = 0.f;
      #pragma unroll
      for (int w = 0; w < NW; ++w) { zs += WRD[w * 132 + r * 32 + e]; ss += WRD[w * 132 + 128 + r]; }
      float zn = zs / ss;
      ZT[e * R + r] = zn;
      float q = half_sum(zn * zn);
      if ((lane & 31) == 31) Z2L[r] = q;
    }
    __syncthreads();
  }

  // ======== iterate: xp = softmax(lpik + lxqik); z = 0.9 z + 0.1 xp@xb^T ========
  // (concat/log_softmax/P_NULL cancels inside softmax.) Pass U computes u (32
  // regs), then u -> p IN PLACE (u dies, one exp per element), then eq-loop.
  for (int st = 0; st < nstep; ++st) {
    float al[R];
    #pragma unroll
    for (int r = 0; r < R; ++r) al[r] = fmaf(Z2L[r], -(1.f / 32.f), -MLD[r]);

    // ---- pass U: up[r][k] = sum_e z[r][e] * xb[e][k] ----
    float up[R][NP][2];
    #pragma unroll
    for (int r = 0; r < R; ++r)
      #pragma unroll
      for (int i = 0; i < NP; ++i) { up[r][i][0] = 0.f; up[r][i][1] = 0.f; }
    #pragma unroll 2
    for (int e = 0; e < Ed; ++e) {
      float4 zv = *reinterpret_cast<const float4*>(&ZT[e * R]);  // broadcast
      float z4[4] = {zv.x, zv.y, zv.z, zv.w};
      #pragma unroll
      for (int i = 0; i < NP; ++i) {
        float2 w = ldw<HW>(xbP, (size_t)e * Kd + i * CS + kb0);
        #pragma unroll
        for (int r = 0; r < R; ++r) {
          up[r][i][0] = fmaf(z4[r], w.x, up[r][i][0]);
          up[r][i][1] = fmaf(z4[r], w.y, up[r][i][1]);
        }
      }
    }

    // ---- u -> p in place; s2 ----
    float s2[R] = {0.f, 0.f, 0.f, 0.f};
    #pragma unroll
    for (int i = 0; i < NP; ++i) {
      #pragma unroll
      for (int r = 0; r < R; ++r) {
        float2 l = *reinterpret_cast<const float2*>(&LP[r * Kd + i * CS + kb0]);
        float p0 = __expf(l.x + al[r] + up[r][i][0] * (1.f / 16.f));
        float p1 = __expf(l.y + al[r] + up[r][i][1] * (1.f / 16.f));
        up[r][i][0] = p0; up[r][i][1] = p1;
        s2[r] += p0 + p1;
      }
    }

    // ---- zacc: EQ=2 chunks over e, eq-loop not unrolled ----
    #pragma unroll 1
    for (int eq = 0; eq < NEQ; ++eq) {
      float zacc[R][EQ];
      #pragma unroll
      for (int r = 0; r < R; ++r)
        #pragma unroll
        for (int e2 = 0; e2 < EQ; ++e2) zacc[r][e2] = 0.f;

      #pragma unroll
      for (int i = 0; i < NP; ++i) {
        #pragma unroll
        for (int e2 = 0; e2 < EQ; ++e2) {
          int e = eq * EQ + e2;
          float2 w = ldw<HW>(xbP, (size_t)e * Kd + i * CS + kb0);
          #pragma unroll
          for (int r = 0; r < R; ++r) {
            zacc[r][e2] = fmaf(up[r][i][0], w.x, zacc[r][e2]);
            zacc[r][e2] = fmaf(up[r][i][1], w.y, zacc[r][e2]);
          }
        }
      }
      #pragma unroll
      for (int r = 0; r < R; ++r)
        #pragma unroll
        for (int e2 = 0; e2 < EQ; ++e2) zacc[r][e2] = wave_sum(zacc[r][e2]);
      if (lane == 63) {
        #pragma unroll
        for (int r = 0; r < R; ++r)
          #pragma unroll
          for (int e2 = 0; e2 < EQ; ++e2)
            WRD[wv * 132 + r * 32 + eq * EQ + e2] = zacc[r][e2];
      }
    }

    #pragma unroll
    for (int r = 0; r < R; ++r) s2[r] = wave_sum(s2[r]);
    if (lane == 63) {
      #pragma unroll
      for (int r = 0; r < R; ++r) WRD[wv * 132 + 128 + r] = s2[r];
    }
    __syncthreads();
    if (tid < 128) {
      int r = tid >> 5, e = tid & 31;
      float zs = 0.f, ss = 0.f;
      #pragma unroll
      for (int w = 0; w < NW; ++w) { zs += WRD[w * 132 + r * 32 + e]; ss += WRD[w * 132 + 128 + r]; }
      float zn = fmaf(0.1f, zs / ss, 0.9f * ZT[e * R + r]);
      ZT[e * R + r] = zn;
      float q = half_sum(zn * zn);
      if ((lane & 31) == 31) Z2L[r] = q;
    }
    __syncthreads();
  }

  // ================= decode pass 1: xq_unnorm = exp(lxqik(z)), S3 ===================
  {
    float u[R][NP][2];
    float cw2[NP][2];  // !HW: w^2 accumulated inline
    #pragma unroll
    for (int r = 0; r < R; ++r)
      #pragma unroll
      for (int i = 0; i < NP; ++i) { u[r][i][0] = 0.f; u[r][i][1] = 0.f; }
    #pragma unroll
    for (int i = 0; i < NP; ++i) { cw2[i][0] = 0.f; cw2[i][1] = 0.f; }

    #pragma unroll 2
    for (int e = 0; e < Ed; ++e) {
      float4 zv = *reinterpret_cast<const float4*>(&ZT[e * R]);
      float z4[4] = {zv.x, zv.y, zv.z, zv.w};
      #pragma unroll
      for (int i = 0; i < NP; ++i) {
        float2 w = ldw<HW>(xbP, (size_t)e * Kd + i * CS + kb0);
        if constexpr (!HW) {
          cw2[i][0] = fmaf(w.x, w.x, cw2[i][0]);
          cw2[i][1] = fmaf(w.y, w.y, cw2[i][1]);
        }
        #pragma unroll
        for (int r = 0; r < R; ++r) {
          u[r][i][0] = fmaf(z4[r], w.x, u[r][i][0]);
          u[r][i][1] = fmaf(z4[r], w.y, u[r][i][1]);
        }
      }
    }

    float s3[R] = {0.f, 0.f, 0.f, 0.f};
    float nz2[R];
    #pragma unroll
    for (int r = 0; r < R; ++r) nz2[r] = Z2L[r] * -(1.f / 32.f);
    #pragma unroll
    for (int i = 0; i < NP; ++i) {
      float cx, cy;
      if constexpr (HW) {
        float2 c = *reinterpret_cast<const float2*>(&cb2P[i * CS + kb0]);
        cx = c.x; cy = c.y;
      } else { cx = cw2[i][0]; cy = cw2[i][1]; }
      #pragma unroll
      for (int r = 0; r < R; ++r) {
        float e0 = __expf(nz2[r] + u[r][i][0] * (1.f / 16.f) - cx * (1.f / 32.f));
        float e1 = __expf(nz2[r] + u[r][i][1] * (1.f / 16.f) - cy * (1.f / 32.f));
        *reinterpret_cast<float2*>(&LP[r * Kd + i * CS + kb0]) = make_float2(e0, e1);
        s3[r] += e0 + e1;
      }
    }
    #pragma unroll
    for (int r = 0; r < R; ++r) s3[r] = wave_sum(s3[r]);
    if (lane == 63) {
      #pragma unroll
      for (int r = 0; r < R; ++r) WRD[wv * 132 + 128 + r] = s3[r];
    }
    __syncthreads();
    if (tid < R) {
      float s = 0.f;
      #pragma unroll
      for (int w = 0; w < NW; ++w) s += WRD[w * 132 + 128 + tid];
      SLD[tid] = 1.f / (PNULLF + s);
    }
    __syncthreads();
  }

  // ================= decode pass 2: y = (xq/den) @ xa^T  (wave-per-g) ===============
  {
    float inv[R];
    #pragma unroll
    for (int r = 0; r < R; ++r) inv[r] = SLD[r];
    float acc[R][4];
    #pragma unroll
    for (int r = 0; r < R; ++r)
      #pragma unroll
      for (int gi = 0; gi < 4; ++gi) acc[r][gi] = 0.f;

    #pragma unroll 2
    for (int c = 0; c < 32; ++c) {
      float xq[R][4];
      #pragma unroll
      for (int r = 0; r < R; ++r) {
        float4 q = *reinterpret_cast<const float4*>(&LP[r * Kd + c * 256 + lane * 4]);
        xq[r][0] = q.x; xq[r][1] = q.y; xq[r][2] = q.z; xq[r][3] = q.w;
      }
      #pragma unroll
      for (int gi = 0; gi < 4; ++gi) {
        int g = gi * NW + wv;
        float4 wa = ld4w<HW>(xaP, (size_t)g * Kd + c * 256 + lane * 4);
        #pragma unroll
        for (int r = 0; r < R; ++r) {
          acc[r][gi] = fmaf(xq[r][0], wa.x, acc[r][gi]);
          acc[r][gi] = fmaf(xq[r][1], wa.y, acc[r][gi]);
          acc[r][gi] = fmaf(xq[r][2], wa.z, acc[r][gi]);
          acc[r][gi] = fmaf(xq[r][3], wa.w, acc[r][gi]);
        }
      }
    }
    #pragma unroll
    for (int r = 0; r < R; ++r)
      #pragma unroll
      for (int gi = 0; gi < 4; ++gi) acc[r][gi] = wave_sum(acc[r][gi]);
    if (lane == 63) {
      #pragma unroll
      for (int r = 0; r < R; ++r)
        #pragma unroll
        for (int gi = 0; gi < 4; ++gi)
          out[(size_t)(rowbase + r) * Gd + gi * NW + wv] = acc[r][gi] * inv[r];
    }
  }
}

// ---- per-call weight conversion: f32 -> f16 + exact column sums of squares ----
__global__ __launch_bounds__(256) void convert_w(
    const float* __restrict__ xa, const float* __restrict__ xb,
    __half* __restrict__ xah, __half* __restrict__ xbh,
    float* __restrict__ c2a, float* __restrict__ cb2)
{
  int k = (int)(blockIdx.x * blockDim.x + threadIdx.x);
  if (k >= Kd) return;
  float s = 0.f;
  #pragma unroll 4
  for (int g = 0; g < Gd; ++g) {
    float v = xa[(size_t)g * Kd + k];
    xah[(size_t)g * Kd + k] = __float2half(v);
    s = fmaf(v, v, s);
  }
  c2a[k] = s;
  s = 0.f;
  #pragma unroll 4
  for (int e = 0; e < Ed; ++e) {
    float v = xb[(size_t)e * Kd + k];
    xbh[(size_t)e * Kd + k] = __float2half(v);
    s = fmaf(v, v, s);
  }
  cb2[k] = s;
}

extern "C" void kernel_launch(void* const* d_in, const int* in_sizes, int n_in,
                              void* d_out, int out_size, void* d_ws, size_t ws_size,
                              hipStream_t stream) {
  const float* images = (const float*)d_in[0];
  const float* xa     = (const float*)d_in[1];
  const float* xb     = (const float*)d_in[2];
  const int*   nstep  = (const int*)d_in[3];
  float* out = (float*)d_out;

  const size_t smem = (size_t)SMEM_FLOATS * sizeof(float);  // 141120 B
  const size_t need = (size_t)(Gd + Ed) * Kd * sizeof(__half) + (size_t)2 * Kd * sizeof(float);

  if (ws_size >= need) {
    __half* xah = (__half*)d_ws;
    __half* xbh = xah + (size_t)Gd * Kd;
    float*  c2a = (float*)(xbh + (size_t)Ed * Kd);
    float*  cb2 = c2a + Kd;
    hipLaunchKernelGGL(convert_w, dim3(Kd / 256), dim3(256), 0, stream,
                       xa, xb, xah, xbh, c2a, cb2);
    (void)hipFuncSetAttribute((const void*)glgae_fused<true>,
                              hipFuncAttributeMaxDynamicSharedMemorySize, (int)smem);
    hipLaunchKernelGGL(glgae_fused<true>, dim3(4096 / R), dim3(T), smem, stream,
                       images, (const void*)xah, (const void*)xbh, c2a, cb2, nstep, out);
  } else {
    (void)hipFuncSetAttribute((const void*)glgae_fused<false>,
                              hipFuncAttributeMaxDynamicSharedMemorySize, (int)smem);
    hipLaunchKernelGGL(glgae_fused<false>, dim3(4096 / R), dim3(T), smem, stream,
                       images, (const void*)xa, (const void*)xb,
                       (const float*)nullptr, (const float*)nullptr, nstep, out);
  }
}

// Round 12
// 745.160 us; speedup vs baseline: 7.3262x; 1.1248x over previous
//
#include <hip/hip_runtime.h>
#include <hip/hip_fp16.h>
#include <math.h>

static constexpr int Gd = 64;     // images feature dim
static constexpr int Ed = 32;     // xb feature dim
static constexpr int Kd = 8192;   // codebook size
static constexpr int R  = 4;      // rows per block
static constexpr int T  = 1024;   // threads per block (16 waves)
static constexpr int NW = 16;     // waves per block
static constexpr int NP = 4;      // float2 pairs per thread (Kd / (2T))
static constexpr int CS = 2 * T;  // k-chunk stride (2048 columns)
static constexpr float PNULLF = 1e-4f;

typedef _Float16 h2v __attribute__((ext_vector_type(2)));

// ---- DPP wave reductions (VALU pipe, no LDS traffic) ----
template<int CTRL, int RMASK>
__device__ __forceinline__ float dpp_add(float v) {
  int t = __builtin_amdgcn_update_dpp(0, __builtin_bit_cast(int, v), CTRL, RMASK, 0xf, true);
  return v + __builtin_bit_cast(float, t);
}
template<int CTRL, int RMASK>
__device__ __forceinline__ float dpp_fmax(float v) {
  int t = __builtin_amdgcn_update_dpp(__builtin_bit_cast(int, -__builtin_inff()),
                                      __builtin_bit_cast(int, v), CTRL, RMASK, 0xf, false);
  return fmaxf(v, __builtin_bit_cast(float, t));
}
__device__ __forceinline__ float wave_sum(float v) {
  v = dpp_add<0x111, 0xf>(v);
  v = dpp_add<0x112, 0xf>(v);
  v = dpp_add<0x114, 0xf>(v);
  v = dpp_add<0x118, 0xf>(v);
  v = dpp_add<0x142, 0xa>(v);
  v = dpp_add<0x143, 0xc>(v);
  return v;  // total in lane 63
}
__device__ __forceinline__ float half_sum(float v) {
  v = dpp_add<0x111, 0xf>(v);
  v = dpp_add<0x112, 0xf>(v);
  v = dpp_add<0x114, 0xf>(v);
  v = dpp_add<0x118, 0xf>(v);
  v = dpp_add<0x142, 0xa>(v);
  return v;  // 32-lane sums in lanes 31, 63
}
__device__ __forceinline__ float wave_max(float v) {
  v = dpp_fmax<0x111, 0xf>(v);
  v = dpp_fmax<0x112, 0xf>(v);
  v = dpp_fmax<0x114, 0xf>(v);
  v = dpp_fmax<0x118, 0xf>(v);
  v = dpp_fmax<0x142, 0xa>(v);
  v = dpp_fmax<0x143, 0xc>(v);
  return v;
}

// ---- f16 dot-pair helpers (1 inst replaces 2 cvt + 2 fma) ----
__device__ __forceinline__ float fdot2(h2v a, h2v b, float c) {
#if defined(__has_builtin)
#if __has_builtin(__builtin_amdgcn_fdot2)
  return __builtin_amdgcn_fdot2(a, b, c, false);
#else
  return fmaf((float)a.x, (float)b.x, fmaf((float)a.y, (float)b.y, c));
#endif
#else
  return fmaf((float)a.x, (float)b.x, fmaf((float)a.y, (float)b.y, c));
#endif
}
__device__ __forceinline__ h2v pkh(float x, float y) {
#if defined(__has_builtin)
#if __has_builtin(__builtin_amdgcn_cvt_pkrtz)
  // builtin returns __fp16 ext_vector(2); bit-identical to h2v -> bit_cast (r9 fix)
  return __builtin_bit_cast(h2v, __builtin_amdgcn_cvt_pkrtz(x, y));
#else
  h2v h; h.x = (_Float16)x; h.y = (_Float16)y; return h;
#endif
#else
  h2v h; h.x = (_Float16)x; h.y = (_Float16)y; return h;
#endif
}
__device__ __forceinline__ h2v bch(unsigned int u) { return __builtin_bit_cast(h2v, u); }
__device__ __forceinline__ unsigned int hbits(h2v h) { return __builtin_bit_cast(unsigned int, h); }

// LDS float offsets
static constexpr int OFF_LP   = 0;                  // [R][Kd]    32768
static constexpr int OFF_IMG  = 32768;              // [Gd][R]    256
static constexpr int OFF_ZT   = 33024;              // [Ed][R]    128
static constexpr int OFF_WRD  = 33152;              // [NW][132]  2112
static constexpr int OFF_MLD  = 35264;              // [4]
static constexpr int OFF_SLD  = 35268;              // [4]
static constexpr int OFF_Z2   = 35272;              // [4]
static constexpr int OFF_X2   = 35276;              // [4]
static constexpr int SMEM_FLOATS = 35280;           // 141120 B

// ======================= main kernel (f16-dot2 path) =========================
// All pair-reductions use v_dot2_f32_f16 (f32 accumulate). Weight layouts:
//   xbh [E][K] f16 (k-pairs)       -> zacc passes
//   xai [G/2][K] u32 (g-pairs)     -> phase A
//   xbi [E/2][K] u32 (e-pairs)     -> U passes
//   xah [G][K] f16                 -> decode2
// Per-thread peak live ~55 VGPR (eq/ep/gp outer loops NOT unrolled: r8-proven
// recipe for no-spill at the allocator's 64-VGPR budget).
__global__ __attribute__((amdgpu_flat_work_group_size(T, T), amdgpu_waves_per_eu(4, 4)))
void glgae_h2(
    const float* __restrict__ images,
    const __half* __restrict__ xah,
    const __half* __restrict__ xbh,
    const unsigned int* __restrict__ xai,
    const unsigned int* __restrict__ xbi,
    const float* __restrict__ c2aP,
    const float* __restrict__ cb2P,
    const int*   __restrict__ nstep_p,
    float* __restrict__ out)
{
  extern __shared__ float sm[];
  float* LP  = sm + OFF_LP;
  float* IMG = sm + OFF_IMG;
  float* ZT  = sm + OFF_ZT;
  float* WRD = sm + OFF_WRD;
  float* MLD = sm + OFF_MLD;
  float* SLD = sm + OFF_SLD;
  float* Z2L = sm + OFF_Z2;
  float* X2L = sm + OFF_X2;
  unsigned int* LPH = reinterpret_cast<unsigned int*>(LP);  // decode xq as h2 pairs

  const int tid  = (int)threadIdx.x;
  const int lane = tid & 63;
  const int wv   = tid >> 6;
  const int rowbase = (int)blockIdx.x * R;
  const int nstep = nstep_p[0];
  const int kb0 = tid * 2;   // k pair base within each 2048-col chunk (even)
  const int kp0 = tid;       // u32-pair index within each 1024-pair chunk

  // ---- stage images transposed: IMG[g][r] ----
  if (tid < Gd * R) {
    int g = tid >> 2, r = tid & 3;
    IMG[g * R + r] = images[(size_t)(rowbase + r) * Gd + g];
  }
  __syncthreads();
  if (tid < R) {
    float s = 0.f;
    #pragma unroll
    for (int g = 0; g < Gd; ++g) { float v = IMG[g * R + tid]; s = fmaf(v, v, s); }
    X2L[tid] = s;
  }
  __syncthreads();  // X2L + IMG ready

  // ================= phase A: lpik = -(x2 - 2 x.xa + c2)/Gd (dot2 over g) =====
  {
    float xk[R][NP][2];
    #pragma unroll
    for (int r = 0; r < R; ++r)
      #pragma unroll
      for (int i = 0; i < NP; ++i) { xk[r][i][0] = 0.f; xk[r][i][1] = 0.f; }

    #pragma unroll 1
    for (int gp = 0; gp < Gd / 2; ++gp) {
      float4 ia = *reinterpret_cast<const float4*>(&IMG[(2 * gp) * R]);
      float4 ib = *reinterpret_cast<const float4*>(&IMG[(2 * gp + 1) * R]);
      h2v imh[4] = {pkh(ia.x, ib.x), pkh(ia.y, ib.y), pkh(ia.z, ib.z), pkh(ia.w, ib.w)};
      #pragma unroll
      for (int i = 0; i < NP; ++i) {
        uint2 w = *reinterpret_cast<const uint2*>(xai + (size_t)gp * Kd + i * CS + kb0);
        h2v w0 = bch(w.x), w1 = bch(w.y);
        #pragma unroll
        for (int r = 0; r < R; ++r) {
          xk[r][i][0] = fdot2(imh[r], w0, xk[r][i][0]);
          xk[r][i][1] = fdot2(imh[r], w1, xk[r][i][1]);
        }
      }
    }

    float mx[R] = {-__builtin_inff(), -__builtin_inff(), -__builtin_inff(), -__builtin_inff()};
    float x2r[R];
    #pragma unroll
    for (int r = 0; r < R; ++r) x2r[r] = X2L[r];
    #pragma unroll
    for (int i = 0; i < NP; ++i) {
      float2 c = *reinterpret_cast<const float2*>(&c2aP[i * CS + kb0]);
      #pragma unroll
      for (int r = 0; r < R; ++r) {
        float v0 = (2.f * xk[r][i][0] - x2r[r] - c.x) * (1.f / 64.f);
        float v1 = (2.f * xk[r][i][1] - x2r[r] - c.y) * (1.f / 64.f);
        mx[r] = fmaxf(mx[r], fmaxf(v0, v1));
        *reinterpret_cast<float2*>(&LP[r * Kd + i * CS + kb0]) = make_float2(v0, v1);
      }
    }
    #pragma unroll
    for (int r = 0; r < R; ++r) mx[r] = wave_max(mx[r]);
    if (lane == 63) {
      #pragma unroll
      for (int r = 0; r < R; ++r) WRD[wv * 132 + 128 + r] = mx[r];
    }
    __syncthreads();
    if (tid < R) {
      float m = -__builtin_inff();
      #pragma unroll
      for (int w = 0; w < NW; ++w) m = fmaxf(m, WRD[w * 132 + 128 + tid]);
      MLD[tid] = m;
    }
    __syncthreads();
  }

  const unsigned int* xbhU = reinterpret_cast<const unsigned int*>(xbh);
  h2v ph[R][NP];   // p packed as half2 pairs (16 u32 regs)

  // ================= encode: z = softmax(lpik) @ xb^T (dot2 over k) ===========
  {
    float s1[R] = {0.f, 0.f, 0.f, 0.f};
    #pragma unroll
    for (int i = 0; i < NP; ++i) {
      #pragma unroll
      for (int r = 0; r < R; ++r) {
        float2 l = *reinterpret_cast<const float2*>(&LP[r * Kd + i * CS + kb0]);
        float m = MLD[r];
        float p0 = __expf(l.x - m);
        float p1 = __expf(l.y - m);
        s1[r] += p0 + p1;
        ph[r][i] = pkh(p0, p1);
      }
    }

    #pragma unroll 1
    for (int eq = 0; eq < 8; ++eq) {
      float acc[R][4];
      #pragma unroll
      for (int r = 0; r < R; ++r)
        #pragma unroll
        for (int e2 = 0; e2 < 4; ++e2) acc[r][e2] = 0.f;
      #pragma unroll
      for (int i = 0; i < NP; ++i) {
        #pragma unroll
        for (int e2 = 0; e2 < 4; ++e2) {
          int e = eq * 4 + e2;
          h2v w = bch(xbhU[(size_t)e * (Kd / 2) + i * (CS / 2) + kp0]);
          #pragma unroll
          for (int r = 0; r < R; ++r) acc[r][e2] = fdot2(ph[r][i], w, acc[r][e2]);
        }
      }
      #pragma unroll
      for (int r = 0; r < R; ++r)
        #pragma unroll
        for (int e2 = 0; e2 < 4; ++e2) acc[r][e2] = wave_sum(acc[r][e2]);
      if (lane == 63) {
        #pragma unroll
        for (int r = 0; r < R; ++r)
          #pragma unroll
          for (int e2 = 0; e2 < 4; ++e2)
            WRD[wv * 132 + r * 32 + eq * 4 + e2] = acc[r][e2];
      }
    }

    #pragma unroll
    for (int r = 0; r < R; ++r) s1[r] = wave_sum(s1[r]);
    if (lane == 63) {
      #pragma unroll
      for (int r = 0; r < R; ++r) WRD[wv * 132 + 128 + r] = s1[r];
    }

    // fold -cb2/32 into LP once
    #pragma unroll
    for (int i = 0; i < NP; ++i) {
      float2 c = *reinterpret_cast<const float2*>(&cb2P[i * CS + kb0]);
      #pragma unroll
      for (int r = 0; r < R; ++r) {
        float2 l = *reinterpret_cast<const float2*>(&LP[r * Kd + i * CS + kb0]);
        l.x -= c.x * (1.f / 32.f);
        l.y -= c.y * (1.f / 32.f);
        *reinterpret_cast<float2*>(&LP[r * Kd + i * CS + kb0]) = l;
      }
    }

    __syncthreads();
    if (tid < 128) {
      int r = tid >> 5, e = tid & 31;
      float zs = 0.f, ss = 0.f;
      #pragma unroll
      for (int w = 0; w < NW; ++w) { zs += WRD[w * 132 + r * 32 + e]; ss += WRD[w * 132 + 128 + r]; }
      float zn = zs / ss;
      ZT[e * R + r] = zn;
      float q = half_sum(zn * zn);
      if ((lane & 31) == 31) Z2L[r] = q;
    }
    __syncthreads();
  }

  // ======== iterate: xp = softmax(lpik + lxqik); z = 0.9 z + 0.1 xp@xb^T ======
  for (int st = 0; st < nstep; ++st) {
    float al[R];
    #pragma unroll
    for (int r = 0; r < R; ++r) al[r] = fmaf(Z2L[r], -(1.f / 32.f), -MLD[r]);

    // ---- pass U (dot2 over e-pairs via xbi) ----
    float u[R][NP][2];
    #pragma unroll
    for (int r = 0; r < R; ++r)
      #pragma unroll
      for (int i = 0; i < NP; ++i) { u[r][i][0] = 0.f; u[r][i][1] = 0.f; }
    #pragma unroll 1
    for (int ep = 0; ep < Ed / 2; ++ep) {
      float4 za = *reinterpret_cast<const float4*>(&ZT[(2 * ep) * R]);
      float4 zb = *reinterpret_cast<const float4*>(&ZT[(2 * ep + 1) * R]);
      h2v zh[4] = {pkh(za.x, zb.x), pkh(za.y, zb.y), pkh(za.z, zb.z), pkh(za.w, zb.w)};
      #pragma unroll
      for (int i = 0; i < NP; ++i) {
        uint2 w = *reinterpret_cast<const uint2*>(xbi + (size_t)ep * Kd + i * CS + kb0);
        h2v w0 = bch(w.x), w1 = bch(w.y);
        #pragma unroll
        for (int r = 0; r < R; ++r) {
          u[r][i][0] = fdot2(zh[r], w0, u[r][i][0]);
          u[r][i][1] = fdot2(zh[r], w1, u[r][i][1]);
        }
      }
    }

    // ---- u -> p (pack to half2), s2 ----
    float s2[R] = {0.f, 0.f, 0.f, 0.f};
    #pragma unroll
    for (int i = 0; i < NP; ++i) {
      #pragma unroll
      for (int r = 0; r < R; ++r) {
        float2 l = *reinterpret_cast<const float2*>(&LP[r * Kd + i * CS + kb0]);
        float p0 = __expf(l.x + al[r] + u[r][i][0] * (1.f / 16.f));
        float p1 = __expf(l.y + al[r] + u[r][i][1] * (1.f / 16.f));
        s2[r] += p0 + p1;
        ph[r][i] = pkh(p0, p1);
      }
    }

    // ---- zacc (dot2 over k) ----
    #pragma unroll 1
    for (int eq = 0; eq < 8; ++eq) {
      float acc[R][4];
      #pragma unroll
      for (int r = 0; r < R; ++r)
        #pragma unroll
        for (int e2 = 0; e2 < 4; ++e2) acc[r][e2] = 0.f;
      #pragma unroll
      for (int i = 0; i < NP; ++i) {
        #pragma unroll
        for (int e2 = 0; e2 < 4; ++e2) {
          int e = eq * 4 + e2;
          h2v w = bch(xbhU[(size_t)e * (Kd / 2) + i * (CS / 2) + kp0]);
          #pragma unroll
          for (int r = 0; r < R; ++r) acc[r][e2] = fdot2(ph[r][i], w, acc[r][e2]);
        }
      }
      #pragma unroll
      for (int r = 0; r < R; ++r)
        #pragma unroll
        for (int e2 = 0; e2 < 4; ++e2) acc[r][e2] = wave_sum(acc[r][e2]);
      if (lane == 63) {
        #pragma unroll
        for (int r = 0; r < R; ++r)
          #pragma unroll
          for (int e2 = 0; e2 < 4; ++e2)
            WRD[wv * 132 + r * 32 + eq * 4 + e2] = acc[r][e2];
      }
    }

    #pragma unroll
    for (int r = 0; r < R; ++r) s2[r] = wave_sum(s2[r]);
    if (lane == 63) {
      #pragma unroll
      for (int r = 0; r < R; ++r) WRD[wv * 132 + 128 + r] = s2[r];
    }
    __syncthreads();
    if (tid < 128) {
      int r = tid >> 5, e = tid & 31;
      float zs = 0.f, ss = 0.f;
      #pragma unroll
      for (int w = 0; w < NW; ++w) { zs += WRD[w * 132 + r * 32 + e]; ss += WRD[w * 132 + 128 + r]; }
      float zn = fmaf(0.1f, zs / ss, 0.9f * ZT[e * R + r]);
      ZT[e * R + r] = zn;
      float q = half_sum(zn * zn);
      if ((lane & 31) == 31) Z2L[r] = q;
    }
    __syncthreads();
  }

  // ========== decode pass 1: xq = exp(lxqik(z)) packed f16, S3 ==========
  {
    float u[R][NP][2];
    #pragma unroll
    for (int r = 0; r < R; ++r)
      #pragma unroll
      for (int i = 0; i < NP; ++i) { u[r][i][0] = 0.f; u[r][i][1] = 0.f; }
    #pragma unroll 1
    for (int ep = 0; ep < Ed / 2; ++ep) {
      float4 za = *reinterpret_cast<const float4*>(&ZT[(2 * ep) * R]);
      float4 zb = *reinterpret_cast<const float4*>(&ZT[(2 * ep + 1) * R]);
      h2v zh[4] = {pkh(za.x, zb.x), pkh(za.y, zb.y), pkh(za.z, zb.z), pkh(za.w, zb.w)};
      #pragma unroll
      for (int i = 0; i < NP; ++i) {
        uint2 w = *reinterpret_cast<const uint2*>(xbi + (size_t)ep * Kd + i * CS + kb0);
        h2v w0 = bch(w.x), w1 = bch(w.y);
        #pragma unroll
        for (int r = 0; r < R; ++r) {
          u[r][i][0] = fdot2(zh[r], w0, u[r][i][0]);
          u[r][i][1] = fdot2(zh[r], w1, u[r][i][1]);
        }
      }
    }

    float s3[R] = {0.f, 0.f, 0.f, 0.f};
    float nz2[R];
    #pragma unroll
    for (int r = 0; r < R; ++r) nz2[r] = Z2L[r] * -(1.f / 32.f);
    __syncthreads();  // all LP (lpik) reads done before LPH overwrite
    #pragma unroll
    for (int i = 0; i < NP; ++i) {
      float2 c = *reinterpret_cast<const float2*>(&cb2P[i * CS + kb0]);
      #pragma unroll
      for (int r = 0; r < R; ++r) {
        float e0 = __expf(nz2[r] + u[r][i][0] * (1.f / 16.f) - c.x * (1.f / 32.f));
        float e1 = __expf(nz2[r] + u[r][i][1] * (1.f / 16.f) - c.y * (1.f / 32.f));
        LPH[r * (Kd / 2) + i * (CS / 2) + kp0] = hbits(pkh(e0, e1));
        s3[r] += e0 + e1;
      }
    }
    #pragma unroll
    for (int r = 0; r < R; ++r) s3[r] = wave_sum(s3[r]);
    if (lane == 63) {
      #pragma unroll
      for (int r = 0; r < R; ++r) WRD[wv * 132 + 128 + r] = s3[r];
    }
    __syncthreads();
    if (tid < R) {
      float s = 0.f;
      #pragma unroll
      for (int w = 0; w < NW; ++w) s += WRD[w * 132 + 128 + tid];
      SLD[tid] = 1.f / (PNULLF + s);
    }
    __syncthreads();
  }

  // ========== decode pass 2: y = (xq/den) @ xa^T (dot2, wave-per-g) ==========
  {
    const unsigned int* xahU = reinterpret_cast<const unsigned int*>(xah);
    float inv[R];
    #pragma unroll
    for (int r = 0; r < R; ++r) inv[r] = SLD[r];
    float acc[R][4];
    #pragma unroll
    for (int r = 0; r < R; ++r)
      #pragma unroll
      for (int gi = 0; gi < 4; ++gi) acc[r][gi] = 0.f;

    #pragma unroll 2
    for (int c = 0; c < 32; ++c) {
      uint2 q[R];
      #pragma unroll
      for (int r = 0; r < R; ++r)
        q[r] = *reinterpret_cast<const uint2*>(&LPH[r * (Kd / 2) + c * 128 + lane * 2]);
      #pragma unroll
      for (int gi = 0; gi < 4; ++gi) {
        int g = gi * NW + wv;
        uint2 wa = *reinterpret_cast<const uint2*>(&xahU[(size_t)g * (Kd / 2) + c * 128 + lane * 2]);
        h2v wa0 = bch(wa.x), wa1 = bch(wa.y);
        #pragma unroll
        for (int r = 0; r < R; ++r) {
          acc[r][gi] = fdot2(bch(q[r].x), wa0, acc[r][gi]);
          acc[r][gi] = fdot2(bch(q[r].y), wa1, acc[r][gi]);
        }
      }
    }
    #pragma unroll
    for (int r = 0; r < R; ++r)
      #pragma unroll
      for (int gi = 0; gi < 4; ++gi) acc[r][gi] = wave_sum(acc[r][gi]);
    if (lane == 63) {
      #pragma unroll
      for (int r = 0; r < R; ++r)
        #pragma unroll
        for (int gi = 0; gi < 4; ++gi)
          out[(size_t)(rowbase + r) * Gd + gi * NW + wv] = acc[r][gi] * inv[r];
    }
  }
}

// =================== fallback kernel (pure f32, r8-proven) ===================
__global__ __attribute__((amdgpu_flat_work_group_size(T, T), amdgpu_waves_per_eu(4, 4)))
void glgae_f32(
    const float* __restrict__ images,
    const float* __restrict__ xa,
    const float* __restrict__ xb,
    const int*   __restrict__ nstep_p,
    float* __restrict__ out)
{
  extern __shared__ float sm[];
  float* LP  = sm + OFF_LP;
  float* IMG = sm + OFF_IMG;
  float* ZT  = sm + OFF_ZT;
  float* WRD = sm + OFF_WRD;
  float* MLD = sm + OFF_MLD;
  float* SLD = sm + OFF_SLD;
  float* Z2L = sm + OFF_Z2;
  float* X2L = sm + OFF_X2;

  const int tid  = (int)threadIdx.x;
  const int lane = tid & 63;
  const int wv   = tid >> 6;
  const int rowbase = (int)blockIdx.x * R;
  const int nstep = nstep_p[0];
  const int kb0 = tid * 2;

  if (tid < Gd * R) {
    int g = tid >> 2, r = tid & 3;
    IMG[g * R + r] = images[(size_t)(rowbase + r) * Gd + g];
  }
  __syncthreads();
  if (tid < R) {
    float s = 0.f;
    #pragma unroll
    for (int g = 0; g < Gd; ++g) { float v = IMG[g * R + tid]; s = fmaf(v, v, s); }
    X2L[tid] = s;
  }

  {
    float xk[R][NP][2];
    float c2l[NP][2];
    #pragma unroll
    for (int r = 0; r < R; ++r)
      #pragma unroll
      for (int i = 0; i < NP; ++i) { xk[r][i][0] = 0.f; xk[r][i][1] = 0.f; }
    #pragma unroll
    for (int i = 0; i < NP; ++i) { c2l[i][0] = 0.f; c2l[i][1] = 0.f; }

    #pragma unroll 2
    for (int g = 0; g < Gd; ++g) {
      float4 imv4 = *reinterpret_cast<const float4*>(&IMG[g * R]);
      float im[4] = {imv4.x, imv4.y, imv4.z, imv4.w};
      #pragma unroll
      for (int i = 0; i < NP; ++i) {
        float2 w = *reinterpret_cast<const float2*>(xa + (size_t)g * Kd + i * CS + kb0);
        c2l[i][0] = fmaf(w.x, w.x, c2l[i][0]);
        c2l[i][1] = fmaf(w.y, w.y, c2l[i][1]);
        #pragma unroll
        for (int r = 0; r < R; ++r) {
          xk[r][i][0] = fmaf(im[r], w.x, xk[r][i][0]);
          xk[r][i][1] = fmaf(im[r], w.y, xk[r][i][1]);
        }
      }
    }
    __syncthreads();

    float mx[R] = {-__builtin_inff(), -__builtin_inff(), -__builtin_inff(), -__builtin_inff()};
    float x2r[R];
    #pragma unroll
    for (int r = 0; r < R; ++r) x2r[r] = X2L[r];
    #pragma unroll
    for (int i = 0; i < NP; ++i) {
      #pragma unroll
      for (int r = 0; r < R; ++r) {
        float v0 = (2.f * xk[r][i][0] - x2r[r] - c2l[i][0]) * (1.f / 64.f);
        float v1 = (2.f * xk[r][i][1] - x2r[r] - c2l[i][1]) * (1.f / 64.f);
        mx[r] = fmaxf(mx[r], fmaxf(v0, v1));
        *reinterpret_cast<float2*>(&LP[r * Kd + i * CS + kb0]) = make_float2(v0, v1);
      }
    }
    #pragma unroll
    for (int r = 0; r < R; ++r) mx[r] = wave_max(mx[r]);
    if (lane == 63) {
      #pragma unroll
      for (int r = 0; r < R; ++r) WRD[wv * 132 + 128 + r] = mx[r];
    }
    __syncthreads();
    if (tid < R) {
      float m = -__builtin_inff();
      #pragma unroll
      for (int w = 0; w < NW; ++w) m = fmaxf(m, WRD[w * 132 + 128 + tid]);
      MLD[tid] = m;
    }
    __syncthreads();
  }

  {
    float p[R][NP][2];
    float s1[R] = {0.f, 0.f, 0.f, 0.f};
    #pragma unroll
    for (int i = 0; i < NP; ++i) {
      #pragma unroll
      for (int r = 0; r < R; ++r) {
        float2 l = *reinterpret_cast<const float2*>(&LP[r * Kd + i * CS + kb0]);
        float m = MLD[r];
        float p0 = __expf(l.x - m);
        float p1 = __expf(l.y - m);
        p[r][i][0] = p0; p[r][i][1] = p1;
        s1[r] += p0 + p1;
      }
    }

    float c2v[NP][2];
    #pragma unroll
    for (int i = 0; i < NP; ++i) { c2v[i][0] = 0.f; c2v[i][1] = 0.f; }

    #pragma unroll 1
    for (int eq = 0; eq < 16; ++eq) {
      float zacc[R][2];
      #pragma unroll
      for (int r = 0; r < R; ++r) { zacc[r][0] = 0.f; zacc[r][1] = 0.f; }
      #pragma unroll
      for (int i = 0; i < NP; ++i) {
        #pragma unroll
        for (int e2 = 0; e2 < 2; ++e2) {
          int e = eq * 2 + e2;
          float2 w = *reinterpret_cast<const float2*>(xb + (size_t)e * Kd + i * CS + kb0);
          c2v[i][0] = fmaf(w.x, w.x, c2v[i][0]);
          c2v[i][1] = fmaf(w.y, w.y, c2v[i][1]);
          #pragma unroll
          for (int r = 0; r < R; ++r) {
            zacc[r][e2] = fmaf(p[r][i][0], w.x, zacc[r][e2]);
            zacc[r][e2] = fmaf(p[r][i][1], w.y, zacc[r][e2]);
          }
        }
      }
      #pragma unroll
      for (int r = 0; r < R; ++r)
        #pragma unroll
        for (int e2 = 0; e2 < 2; ++e2) zacc[r][e2] = wave_sum(zacc[r][e2]);
      if (lane == 63) {
        #pragma unroll
        for (int r = 0; r < R; ++r)
          #pragma unroll
          for (int e2 = 0; e2 < 2; ++e2)
            WRD[wv * 132 + r * 32 + eq * 2 + e2] = zacc[r][e2];
      }
    }

    #pragma unroll
    for (int r = 0; r < R; ++r) s1[r] = wave_sum(s1[r]);
    if (lane == 63) {
      #pragma unroll
      for (int r = 0; r < R; ++r) WRD[wv * 132 + 128 + r] = s1[r];
    }

    #pragma unroll
    for (int i = 0; i < NP; ++i) {
      #pragma unroll
      for (int r = 0; r < R; ++r) {
        float2 l = *reinterpret_cast<const float2*>(&LP[r * Kd + i * CS + kb0]);
        l.x -= c2v[i][0] * (1.f / 32.f);
        l.y -= c2v[i][1] * (1.f / 32.f);
        *reinterpret_cast<float2*>(&LP[r * Kd + i * CS + kb0]) = l;
      }
    }

    __syncthreads();
    if (tid < 128) {
      int r = tid >> 5, e = tid & 31;
      float zs = 0.f, ss = 0.f;
      #pragma unroll
      for (int w = 0; w < NW; ++w) { zs += WRD[w * 132 + r * 32 + e]; ss += WRD[w * 132 + 128 + r]; }
      float zn = zs / ss;
      ZT[e * R + r] = zn;
      float q = half_sum(zn * zn);
      if ((lane & 31) == 31) Z2L[r] = q;
    }
    __syncthreads();
  }

  for (int st = 0; st < nstep; ++st) {
    float al[R];
    #pragma unroll
    for (int r = 0; r < R; ++r) al[r] = fmaf(Z2L[r], -(1.f / 32.f), -MLD[r]);

    float up[R][NP][2];
    #pragma unroll
    for (int r = 0; r < R; ++r)
      #pragma unroll
      for (int i = 0; i < NP; ++i) { up[r][i][0] = 0.f; up[r][i][1] = 0.f; }
    #pragma unroll 2
    for (int e = 0; e < Ed; ++e) {
      float4 zv = *reinterpret_cast<const float4*>(&ZT[e * R]);
      float z4[4] = {zv.x, zv.y, zv.z, zv.w};
      #pragma unroll
      for (int i = 0; i < NP; ++i) {
        float2 w = *reinterpret_cast<const float2*>(xb + (size_t)e * Kd + i * CS + kb0);
        #pragma unroll
        for (int r = 0; r < R; ++r) {
          up[r][i][0] = fmaf(z4[r], w.x, up[r][i][0]);
          up[r][i][1] = fmaf(z4[r], w.y, up[r][i][1]);
        }
      }
    }

    float s2[R] = {0.f, 0.f, 0.f, 0.f};
    #pragma unroll
    for (int i = 0; i < NP; ++i) {
      #pragma unroll
      for (int r = 0; r < R; ++r) {
        float2 l = *reinterpret_cast<const float2*>(&LP[r * Kd + i * CS + kb0]);
        float p0 = __expf(l.x + al[r] + up[r][i][0] * (1.f / 16.f));
        float p1 = __expf(l.y + al[r] + up[r][i][1] * (1.f / 16.f));
        up[r][i][0] = p0; up[r][i][1] = p1;
        s2[r] += p0 + p1;
      }
    }

    #pragma unroll 1
    for (int eq = 0; eq < 16; ++eq) {
      float zacc[R][2];
      #pragma unroll
      for (int r = 0; r < R; ++r) { zacc[r][0] = 0.f; zacc[r][1] = 0.f; }
      #pragma unroll
      for (int i = 0; i < NP; ++i) {
        #pragma unroll
        for (int e2 = 0; e2 < 2; ++e2) {
          int e = eq * 2 + e2;
          float2 w = *reinterpret_cast<const float2*>(xb + (size_t)e * Kd + i * CS + kb0);
          #pragma unroll
          for (int r = 0; r < R; ++r) {
            zacc[r][e2] = fmaf(up[r][i][0], w.x, zacc[r][e2]);
            zacc[r][e2] = fmaf(up[r][i][1], w.y, zacc[r][e2]);
          }
        }
      }
      #pragma unroll
      for (int r = 0; r < R; ++r)
        #pragma unroll
        for (int e2 = 0; e2 < 2; ++e2) zacc[r][e2] = wave_sum(zacc[r][e2]);
      if (lane == 63) {
        #pragma unroll
        for (int r = 0; r < R; ++r)
          #pragma unroll
          for (int e2 = 0; e2 < 2; ++e2)
            WRD[wv * 132 + r * 32 + eq * 2 + e2] = zacc[r][e2];
      }
    }

    #pragma unroll
    for (int r = 0; r < R; ++r) s2[r] = wave_sum(s2[r]);
    if (lane == 63) {
      #pragma unroll
      for (int r = 0; r < R; ++r) WRD[wv * 132 + 128 + r] = s2[r];
    }
    __syncthreads();
    if (tid < 128) {
      int r = tid >> 5, e = tid & 31;
      float zs = 0.f, ss = 0.f;
      #pragma unroll
      for (int w = 0; w < NW; ++w) { zs += WRD[w * 132 + r * 32 + e]; ss += WRD[w * 132 + 128 + r]; }
      float zn = fmaf(0.1f, zs / ss, 0.9f * ZT[e * R + r]);
      ZT[e * R + r] = zn;
      float q = half_sum(zn * zn);
      if ((lane & 31) == 31) Z2L[r] = q;
    }
    __syncthreads();
  }

  {
    float u[R][NP][2];
    float cw2[NP][2];
    #pragma unroll
    for (int r = 0; r < R; ++r)
      #pragma unroll
      for (int i = 0; i < NP; ++i) { u[r][i][0] = 0.f; u[r][i][1] = 0.f; }
    #pragma unroll
    for (int i = 0; i < NP; ++i) { cw2[i][0] = 0.f; cw2[i][1] = 0.f; }

    #pragma unroll 2
    for (int e = 0; e < Ed; ++e) {
      float4 zv = *reinterpret_cast<const float4*>(&ZT[e * R]);
      float z4[4] = {zv.x, zv.y, zv.z, zv.w};
      #pragma unroll
      for (int i = 0; i < NP; ++i) {
        float2 w = *reinterpret_cast<const float2*>(xb + (size_t)e * Kd + i * CS + kb0);
        cw2[i][0] = fmaf(w.x, w.x, cw2[i][0]);
        cw2[i][1] = fmaf(w.y, w.y, cw2[i][1]);
        #pragma unroll
        for (int r = 0; r < R; ++r) {
          u[r][i][0] = fmaf(z4[r], w.x, u[r][i][0]);
          u[r][i][1] = fmaf(z4[r], w.y, u[r][i][1]);
        }
      }
    }

    float s3[R] = {0.f, 0.f, 0.f, 0.f};
    float nz2[R];
    #pragma unroll
    for (int r = 0; r < R; ++r) nz2[r] = Z2L[r] * -(1.f / 32.f);
    #pragma unroll
    for (int i = 0; i < NP; ++i) {
      #pragma unroll
      for (int r = 0; r < R; ++r) {
        float e0 = __expf(nz2[r] + u[r][i][0] * (1.f / 16.f) - cw2[i][0] * (1.f / 32.f));
        float e1 = __expf(nz2[r] + u[r][i][1] * (1.f / 16.f) - cw2[i][1] * (1.f / 32.f));
        *reinterpret_cast<float2*>(&LP[r * Kd + i * CS + kb0]) = make_float2(e0, e1);
        s3[r] += e0 + e1;
      }
    }
    #pragma unroll
    for (int r = 0; r < R; ++r) s3[r] = wave_sum(s3[r]);
    if (lane == 63) {
      #pragma unroll
      for (int r = 0; r < R; ++r) WRD[wv * 132 + 128 + r] = s3[r];
    }
    __syncthreads();
    if (tid < R) {
      float s = 0.f;
      #pragma unroll
      for (int w = 0; w < NW; ++w) s += WRD[w * 132 + 128 + tid];
      SLD[tid] = 1.f / (PNULLF + s);
    }
    __syncthreads();
  }

  {
    float inv[R];
    #pragma unroll
    for (int r = 0; r < R; ++r) inv[r] = SLD[r];
    float acc[R][4];
    #pragma unroll
    for (int r = 0; r < R; ++r)
      #pragma unroll
      for (int gi = 0; gi < 4; ++gi) acc[r][gi] = 0.f;

    #pragma unroll 2
    for (int c = 0; c < 32; ++c) {
      float xq[R][4];
      #pragma unroll
      for (int r = 0; r < R; ++r) {
        float4 q = *reinterpret_cast<const float4*>(&LP[r * Kd + c * 256 + lane * 4]);
        xq[r][0] = q.x; xq[r][1] = q.y; xq[r][2] = q.z; xq[r][3] = q.w;
      }
      #pragma unroll
      for (int gi = 0; gi < 4; ++gi) {
        int g = gi * NW + wv;
        float4 wa = *reinterpret_cast<const float4*>(xa + (size_t)g * Kd + c * 256 + lane * 4);
        #pragma unroll
        for (int r = 0; r < R; ++r) {
          acc[r][gi] = fmaf(xq[r][0], wa.x, acc[r][gi]);
          acc[r][gi] = fmaf(xq[r][1], wa.y, acc[r][gi]);
          acc[r][gi] = fmaf(xq[r][2], wa.z, acc[r][gi]);
          acc[r][gi] = fmaf(xq[r][3], wa.w, acc[r][gi]);
        }
      }
    }
    #pragma unroll
    for (int r = 0; r < R; ++r)
      #pragma unroll
      for (int gi = 0; gi < 4; ++gi) acc[r][gi] = wave_sum(acc[r][gi]);
    if (lane == 63) {
      #pragma unroll
      for (int r = 0; r < R; ++r)
        #pragma unroll
        for (int gi = 0; gi < 4; ++gi)
          out[(size_t)(rowbase + r) * Gd + gi * NW + wv] = acc[r][gi] * inv[r];
    }
  }
}

// ---- per-call weight conversion: f16 copies + pair-interleaved layouts ----
__global__ __launch_bounds__(256) void convert_w(
    const float* __restrict__ xa, const float* __restrict__ xb,
    __half* __restrict__ xah, __half* __restrict__ xbh,
    unsigned int* __restrict__ xai, unsigned int* __restrict__ xbi,
    float* __restrict__ c2a, float* __restrict__ cb2)
{
  int k = (int)(blockIdx.x * blockDim.x + threadIdx.x);
  if (k >= Kd) return;
  float s = 0.f;
  #pragma unroll 2
  for (int gp = 0; gp < Gd / 2; ++gp) {
    float va = xa[(size_t)(2 * gp) * Kd + k];
    float vb = xa[(size_t)(2 * gp + 1) * Kd + k];
    __half ha = __float2half(va), hb = __float2half(vb);
    xah[(size_t)(2 * gp) * Kd + k] = ha;
    xah[(size_t)(2 * gp + 1) * Kd + k] = hb;
    __half2 hh; hh.x = ha; hh.y = hb;
    xai[(size_t)gp * Kd + k] = *reinterpret_cast<unsigned int*>(&hh);
    s = fmaf(va, va, fmaf(vb, vb, s));
  }
  c2a[k] = s;
  s = 0.f;
  #pragma unroll 2
  for (int ep = 0; ep < Ed / 2; ++ep) {
    float va = xb[(size_t)(2 * ep) * Kd + k];
    float vb = xb[(size_t)(2 * ep + 1) * Kd + k];
    __half ha = __float2half(va), hb = __float2half(vb);
    xbh[(size_t)(2 * ep) * Kd + k] = ha;
    xbh[(size_t)(2 * ep + 1) * Kd + k] = hb;
    __half2 hh; hh.x = ha; hh.y = hb;
    xbi[(size_t)ep * Kd + k] = *reinterpret_cast<unsigned int*>(&hh);
    s = fmaf(va, va, fmaf(vb, vb, s));
  }
  cb2[k] = s;
}

extern "C" void kernel_launch(void* const* d_in, const int* in_sizes, int n_in,
                              void* d_out, int out_size, void* d_ws, size_t ws_size,
                              hipStream_t stream) {
  const float* images = (const float*)d_in[0];
  const float* xa     = (const float*)d_in[1];
  const float* xb     = (const float*)d_in[2];
  const int*   nstep  = (const int*)d_in[3];
  float* out = (float*)d_out;

  const size_t smem = (size_t)SMEM_FLOATS * sizeof(float);  // 141120 B
  const size_t szXah = (size_t)Gd * Kd * sizeof(__half);          // 1 MB
  const size_t szXbh = (size_t)Ed * Kd * sizeof(__half);          // 0.5 MB
  const size_t szXai = (size_t)(Gd / 2) * Kd * sizeof(unsigned);  // 1 MB
  const size_t szXbi = (size_t)(Ed / 2) * Kd * sizeof(unsigned);  // 0.5 MB
  const size_t szC   = (size_t)Kd * sizeof(float);                // 32 KB
  const size_t need = szXah + szXbh + szXai + szXbi + 2 * szC;

  if (ws_size >= need) {
    char* w = (char*)d_ws;
    __half* xah = (__half*)w;                w += szXah;
    __half* xbh = (__half*)w;                w += szXbh;
    unsigned int* xai = (unsigned int*)w;    w += szXai;
    unsigned int* xbi = (unsigned int*)w;    w += szXbi;
    float* c2a = (float*)w;                  w += szC;
    float* cb2 = (float*)w;
    hipLaunchKernelGGL(convert_w, dim3(Kd / 256), dim3(256), 0, stream,
                       xa, xb, xah, xbh, xai, xbi, c2a, cb2);
    (void)hipFuncSetAttribute((const void*)glgae_h2,
                              hipFuncAttributeMaxDynamicSharedMemorySize, (int)smem);
    hipLaunchKernelGGL(glgae_h2, dim3(4096 / R), dim3(T), smem, stream,
                       images, xah, xbh, xai, xbi, c2a, cb2, nstep, out);
  } else {
    (void)hipFuncSetAttribute((const void*)glgae_f32,
                              hipFuncAttributeMaxDynamicSharedMemorySize, (int)smem);
    hipLaunchKernelGGL(glgae_f32, dim3(4096 / R), dim3(T), smem, stream,
                       images, xa, xb, nstep, out);
  }
}